// Round 11
// baseline (529.703 us; speedup 1.0000x reference)
//
#include <hip/hip_runtime.h>
#include <math.h>

#define N0 100000
#define N1 20000
#define N2 4000
#define HDIM 128
#define E0C 1600000
#define E1C 320000
#define E2C 64000
#define EPSBN 1e-5f

typedef unsigned int u32;
typedef float f32x4 __attribute__((ext_vector_type(4)));
typedef short bf16x8 __attribute__((ext_vector_type(8)));

union FragU { uint4 u; bf16x8 h; };
__device__ __forceinline__ bf16x8 asbf(uint4 v) { FragU x; x.u = v; return x.h; }

// bf16 pair helpers: low half = feature 2k, high half = feature 2k+1
__device__ __forceinline__ float bl(u32 p) { return __uint_as_float(p << 16); }
__device__ __forceinline__ float bh(u32 p) { return __uint_as_float(p & 0xFFFF0000u); }
__device__ __forceinline__ u32 pack2(float a, float b) {
    u32 ua = __float_as_uint(a), ub = __float_as_uint(b);
    ua = (ua + 0x7FFFu + ((ua >> 16) & 1u)) >> 16;
    ub = (ub + 0x7FFFu + ((ub >> 16) & 1u)) >> 16;
    return ua | (ub << 16);
}

// concatenated count-array layout (destination-count arrays)
#define OFF0 0
#define OFF1 (N0)
#define OFF2 (N0 + N1)
#define OFF3 (N0 + N1 + N2)
#define OFF4 (N0 + N1 + N2 + N1)
#define OFFT (N0 + N1 + N2 + N1 + N2)       // 148000
#define NBLK ((OFFT + 1023) / 1024)          // 145

// concatenated work-item layout (edges + parent links)
#define S0 (E0C)
#define S1 (E0C + E1C)
#define S2 (E0C + E1C + E2C)
#define S3 (E0C + E1C + E2C + N0)
#define S4 (E0C + E1C + E2C + N0 + N1)
#define TQ ((S4 + 3) / 4)                    // threads for 4-way unrolled passes

// ---------------- CSR build kernels ----------------

__device__ __forceinline__ void item_src(int g,
    const int* ei0c, const int* ei1c, const int* ei2c,
    const int* p1, const int* p2, int& x, int& off)
{
    if (g < S0)      { x = ei0c[g];      off = OFF0; }
    else if (g < S1) { x = ei1c[g - S0]; off = OFF1; }
    else if (g < S2) { x = ei2c[g - S1]; off = OFF2; }
    else if (g < S3) { x = p1[g - S2];   off = OFF3; }
    else             { x = p2[g - S3];   off = OFF4; }
}

// 4-way unrolled histogram + rank: 4 independent atomics in flight per thread
__global__ __launch_bounds__(256) void count_all_kernel(
    const int* __restrict__ ei0c, const int* __restrict__ ei1c, const int* __restrict__ ei2c,
    const int* __restrict__ p1, const int* __restrict__ p2,
    int* __restrict__ cnt, int* __restrict__ rank)
{
    int t = blockIdx.x * blockDim.x + threadIdx.x;
    if (t >= TQ) return;
    int idx[4]; bool v[4];
    int xs[4], os[4];
    #pragma unroll
    for (int k = 0; k < 4; k++) {
        idx[k] = t + k * TQ;
        v[k] = idx[k] < S4;
        if (v[k]) item_src(idx[k], ei0c, ei1c, ei2c, p1, p2, xs[k], os[k]);
    }
    int r[4];
    #pragma unroll
    for (int k = 0; k < 4; k++)
        if (v[k]) r[k] = atomicAdd(&cnt[os[k] + xs[k]], 1);
    #pragma unroll
    for (int k = 0; k < 4; k++)
        if (v[k]) rank[idx[k]] = r[k];
}

__global__ __launch_bounds__(256) void scan_k1(const int* __restrict__ c, int* __restrict__ bsum, int n) {
    int t = threadIdx.x;
    int base = blockIdx.x * 1024 + t * 4;
    int s = 0;
    #pragma unroll
    for (int j = 0; j < 4; j++) {
        int idx = base + j;
        if (idx < n) s += c[idx];
    }
    #pragma unroll
    for (int o = 32; o > 0; o >>= 1) s += __shfl_down(s, o, 64);
    __shared__ int ws[4];
    if ((t & 63) == 0) ws[t >> 6] = s;
    __syncthreads();
    if (t == 0) bsum[blockIdx.x] = ws[0] + ws[1] + ws[2] + ws[3];
}

__global__ __launch_bounds__(256) void scan_k2(int* __restrict__ bsum, int* __restrict__ totalOut, int nb) {
    int t = threadIdx.x;
    int v = (t < nb) ? bsum[t] : 0;
    __shared__ int ts[256];
    ts[t] = v;
    __syncthreads();
    for (int o = 1; o < 256; o <<= 1) {
        int u = (t >= o) ? ts[t - o] : 0;
        __syncthreads();
        ts[t] += u;
        __syncthreads();
    }
    if (t < nb) bsum[t] = ts[t] - v;
    if (t == nb - 1) *totalOut = ts[t];
}

__global__ __launch_bounds__(256) void scan_k3(const int* __restrict__ c, const int* __restrict__ bsum,
                                               const int* __restrict__ total,
                                               int* __restrict__ S, int n) {
    int t = threadIdx.x;
    int base = blockIdx.x * 1024 + t * 4;
    int v[4];
    #pragma unroll
    for (int j = 0; j < 4; j++) v[j] = (base + j < n) ? c[base + j] : 0;
    int tsum = v[0] + v[1] + v[2] + v[3];
    __shared__ int ts[256];
    ts[t] = tsum;
    __syncthreads();
    for (int o = 1; o < 256; o <<= 1) {
        int u = (t >= o) ? ts[t - o] : 0;
        __syncthreads();
        ts[t] += u;
        __syncthreads();
    }
    int run = bsum[blockIdx.x] + ts[t] - tsum;
    #pragma unroll
    for (int j = 0; j < 4; j++) {
        if (base + j < n) { S[base + j] = run; run += v[j]; }
    }
    if (blockIdx.x == 0 && t == 0) S[n] = *total;
}

__global__ __launch_bounds__(256) void csr_fixup_kernel(
    const int* __restrict__ S, const int* __restrict__ cntBase,
    int* __restrict__ rp0, float* __restrict__ dis0,
    int* __restrict__ rp1, float* __restrict__ dis1,
    int* __restrict__ rp2, float* __restrict__ dis2,
    int* __restrict__ pp1, int* __restrict__ pp2)
{
    int g = blockIdx.x * blockDim.x + threadIdx.x;
    if (g >= OFFT) return;
    int s = S[g];
    if (g < OFF1) {
        int i = g;
        rp0[i] = s - S[OFF0];
        dis0[i] = rsqrtf((float)(cntBase[g] + 1));
        if (i == 0) rp0[N0] = S[OFF1] - S[OFF0];
    } else if (g < OFF2) {
        int i = g - OFF1;
        rp1[i] = s - S[OFF1];
        dis1[i] = rsqrtf((float)(cntBase[g] + 1));
        if (i == 0) rp1[N1] = S[OFF2] - S[OFF1];
    } else if (g < OFF3) {
        int i = g - OFF2;
        rp2[i] = s - S[OFF2];
        dis2[i] = rsqrtf((float)(cntBase[g] + 1));
        if (i == 0) rp2[N2] = S[OFF3] - S[OFF2];
    } else if (g < OFF4) {
        int i = g - OFF3;
        pp1[i] = s - S[OFF3];
        if (i == 0) pp1[N1] = S[OFF4] - S[OFF3];
    } else {
        int i = g - OFF4;
        pp2[i] = s - S[OFF4];
        if (i == 0) pp2[N2] = S[OFFT] - S[OFF4];
    }
}

// atomic-free fill, 4-way unrolled for MLP
__global__ __launch_bounds__(256) void fill_all_kernel(
    const int* __restrict__ ei0r, const int* __restrict__ ei0c,
    const int* __restrict__ ei1r, const int* __restrict__ ei1c,
    const int* __restrict__ ei2r, const int* __restrict__ ei2c,
    const int* __restrict__ p1, const int* __restrict__ p2,
    const int* __restrict__ rank,
    const int* __restrict__ rp0, const int* __restrict__ rp1, const int* __restrict__ rp2,
    const int* __restrict__ pp1, const int* __restrict__ pp2,
    int* __restrict__ src0, int* __restrict__ src1, int* __restrict__ src2,
    int* __restrict__ child1, int* __restrict__ child2)
{
    int t = blockIdx.x * blockDim.x + threadIdx.x;
    if (t >= TQ) return;
    #pragma unroll
    for (int k = 0; k < 4; k++) {
        int g = t + k * TQ;
        if (g >= S4) break;
        int r = rank[g];
        if (g < S0) {
            src0[rp0[ei0c[g]] + r] = ei0r[g];
        } else if (g < S1) {
            int i = g - S0;
            src1[rp1[ei1c[i]] + r] = ei1r[i];
        } else if (g < S2) {
            int i = g - S1;
            src2[rp2[ei2c[i]] + r] = ei2r[i];
        } else if (g < S3) {
            int i = g - S2;
            child1[pp1[p1[i]] + r] = i;
        } else {
            int i = g - S3;
            child2[pp2[p2[i]] + r] = i;
        }
    }
}

__global__ void bn_pre_kernel(const float* __restrict__ g, const float* __restrict__ beta,
                              const float* __restrict__ mean, const float* __restrict__ var,
                              float* __restrict__ scale, float* __restrict__ shift) {
    int i = blockIdx.x * blockDim.x + threadIdx.x;
    if (i < 4 * HDIM) {
        float s = g[i] * rsqrtf(var[i] + EPSBN);
        scale[i] = s;
        shift[i] = beta[i] - mean[i] * s;
    }
}

// ---------------- gather kernels (bf16 features, fp32 accumulate) ----------------

__global__ __launch_bounds__(256) void gather128_kernel(
    const int* __restrict__ rp, const int* __restrict__ srcl,
    const u32* __restrict__ y, const float* __restrict__ dis,
    const float* __restrict__ bias, u32* __restrict__ h, int n)
{
    int wid = (int)((blockIdx.x * 256 + threadIdx.x) >> 6);
    int lane = threadIdx.x & 63;
    if (wid >= n) return;
    u32 self = y[(long long)wid * 64 + lane];
    float ax = bl(self), ay = bh(self);
    int e = rp[wid], e1 = rp[wid + 1];
    for (; e + 3 < e1; e += 4) {
        int s0 = srcl[e], s1 = srcl[e + 1], s2 = srcl[e + 2], s3 = srcl[e + 3];
        u32 p0 = y[(long long)s0 * 64 + lane];
        u32 p1 = y[(long long)s1 * 64 + lane];
        u32 p2 = y[(long long)s2 * 64 + lane];
        u32 p3 = y[(long long)s3 * 64 + lane];
        ax += (bl(p0) + bl(p1)) + (bl(p2) + bl(p3));
        ay += (bh(p0) + bh(p1)) + (bh(p2) + bh(p3));
    }
    if (e + 1 < e1) {
        u32 p0 = y[(long long)srcl[e] * 64 + lane];
        u32 p1 = y[(long long)srcl[e + 1] * 64 + lane];
        ax += bl(p0) + bl(p1);
        ay += bh(p0) + bh(p1);
        e += 2;
    }
    if (e < e1) {
        u32 p = y[(long long)srcl[e] * 64 + lane];
        ax += bl(p); ay += bh(p);
    }
    float d = dis[wid];
    float2 b = ((const float2*)bias)[lane];
    float r0 = fmaxf(fmaf(d, ax, b.x), 0.f);
    float r1 = fmaxf(fmaf(d, ay, b.y), 0.f);
    h[(long long)wid * 64 + lane] = pack2(r0, r1);
}

__global__ __launch_bounds__(256) void gatherP_kernel(
    const int* __restrict__ pp, const int* __restrict__ childl,
    const u32* __restrict__ h, u32* __restrict__ p, int n)
{
    int wid = (int)((blockIdx.x * 256 + threadIdx.x) >> 6);
    int lane = threadIdx.x & 63;
    if (wid >= n) return;
    float ax = 0.f, ay = 0.f;
    int e = pp[wid], e1 = pp[wid + 1];
    for (; e + 3 < e1; e += 4) {
        int s0 = childl[e], s1 = childl[e + 1], s2 = childl[e + 2], s3 = childl[e + 3];
        u32 p0 = h[(long long)s0 * 64 + lane];
        u32 p1 = h[(long long)s1 * 64 + lane];
        u32 p2 = h[(long long)s2 * 64 + lane];
        u32 p3 = h[(long long)s3 * 64 + lane];
        ax += (bl(p0) + bl(p1)) + (bl(p2) + bl(p3));
        ay += (bh(p0) + bh(p1)) + (bh(p2) + bh(p3));
    }
    if (e + 1 < e1) {
        u32 p0 = h[(long long)childl[e] * 64 + lane];
        u32 p1 = h[(long long)childl[e + 1] * 64 + lane];
        ax += bl(p0) + bl(p1);
        ay += bh(p0) + bh(p1);
        e += 2;
    }
    if (e < e1) {
        u32 q = h[(long long)childl[e] * 64 + lane];
        ax += bl(q); ay += bh(q);
    }
    p[(long long)wid * 64 + lane] = pack2(ax, ay);
}

// Final: gather bf16-packed 32B rows (5 u32 payload, stride 8) + bias + log_softmax
__global__ __launch_bounds__(256) void gather10_lsm_kernel(
    const int* __restrict__ rp, const int* __restrict__ srcl,
    const u32* __restrict__ y4, const float* __restrict__ dis,
    const float* __restrict__ bias, float* __restrict__ out, int n)
{
    int c = blockIdx.x * blockDim.x + threadIdx.x;
    if (c >= n) return;
    float acc[10];
    {
        long long base = (long long)c * 8;
        uint4 q = *(const uint4*)(y4 + base);
        u32 q4 = y4[base + 4];
        acc[0] = bl(q.x); acc[1] = bh(q.x);
        acc[2] = bl(q.y); acc[3] = bh(q.y);
        acc[4] = bl(q.z); acc[5] = bh(q.z);
        acc[6] = bl(q.w); acc[7] = bh(q.w);
        acc[8] = bl(q4);  acc[9] = bh(q4);
    }
    int e = rp[c], e1 = rp[c + 1];
    for (; e + 1 < e1; e += 2) {
        long long bA = (long long)srcl[e] * 8;
        long long bB = (long long)srcl[e + 1] * 8;
        uint4 qa = *(const uint4*)(y4 + bA);
        u32 qa4 = y4[bA + 4];
        uint4 qb = *(const uint4*)(y4 + bB);
        u32 qb4 = y4[bB + 4];
        acc[0] += bl(qa.x) + bl(qb.x); acc[1] += bh(qa.x) + bh(qb.x);
        acc[2] += bl(qa.y) + bl(qb.y); acc[3] += bh(qa.y) + bh(qb.y);
        acc[4] += bl(qa.z) + bl(qb.z); acc[5] += bh(qa.z) + bh(qb.z);
        acc[6] += bl(qa.w) + bl(qb.w); acc[7] += bh(qa.w) + bh(qb.w);
        acc[8] += bl(qa4) + bl(qb4);   acc[9] += bh(qa4) + bh(qb4);
    }
    if (e < e1) {
        long long bA = (long long)srcl[e] * 8;
        uint4 qa = *(const uint4*)(y4 + bA);
        u32 qa4 = y4[bA + 4];
        acc[0] += bl(qa.x); acc[1] += bh(qa.x);
        acc[2] += bl(qa.y); acc[3] += bh(qa.y);
        acc[4] += bl(qa.z); acc[5] += bh(qa.z);
        acc[6] += bl(qa.w); acc[7] += bh(qa.w);
        acc[8] += bl(qa4);  acc[9] += bh(qa4);
    }
    float d = dis[c];
    float m = -1e30f;
    #pragma unroll
    for (int k = 0; k < 10; k++) {
        acc[k] = fmaf(d, acc[k], bias[k]);
        m = fmaxf(m, acc[k]);
    }
    float s = 0.f;
    #pragma unroll
    for (int k = 0; k < 10; k++) s += expf(acc[k] - m);
    float ls = logf(s);
    #pragma unroll
    for (int k = 0; k < 10; k++) out[(long long)c * 10 + k] = acc[k] - m - ls;
}

// ---------------- MFMA matmul K=128, N=128 ----------------
// D = X @ W via mfma_f32_16x16x32_bf16 with W in A slot, X rows in B slot.
// C/D layout: col'=lane&15 (= X row), row'=quad*4+reg (= W col) -> lane holds 4
// consecutive output cols of one row => direct bf16-pair packing, no shuffle.
__global__ __launch_bounds__(256) void mm128_kernel(
    const void* __restrict__ Av, const float* __restrict__ W,
    u32* __restrict__ out, int M,
    const float* __restrict__ dis,
    const u32* __restrict__ gsrc, const int* __restrict__ gidx,
    const float* __restrict__ bias,
    const float* __restrict__ bnscale, const float* __restrict__ bnshift,
    int pool, int afp32)
{
    __shared__ u32 WL[8192];   // [t=8][s=4][lane=64][i=4]
    int tid = threadIdx.x;

    // stage W -> bf16 fragments: frag(t,s,lane=(q,m))[j] = W[s*32+q*8+j][t*16+m]
    #pragma unroll
    for (int it = 0; it < 32; it++) {
        int flat = it * 256 + tid;
        int i = flat & 3;
        int ln = (flat >> 2) & 63;
        int s = (flat >> 8) & 3;
        int t = flat >> 10;
        int mm = ln & 15, qq = ln >> 4;
        int k0 = s * 32 + qq * 8 + 2 * i;
        int col = t * 16 + mm;
        WL[flat] = pack2(W[k0 * 128 + col], W[(k0 + 1) * 128 + col]);
    }
    __syncthreads();

    int lane = tid & 63;
    int w = tid >> 6;
    int m = lane & 15, q = lane >> 4;
    int row = blockIdx.x * 64 + w * 16 + m;
    bool live = (row < M);

    uint4 xb[4];
    if (live) {
        if (afp32) {
            const float* Af = (const float*)Av;
            #pragma unroll
            for (int s = 0; s < 4; s++) {
                const float4* p = (const float4*)(Af + (long long)row * 128 + s * 32 + q * 8);
                float4 f0 = p[0], f1 = p[1];
                xb[s].x = pack2(f0.x, f0.y);
                xb[s].y = pack2(f0.z, f0.w);
                xb[s].z = pack2(f1.x, f1.y);
                xb[s].w = pack2(f1.z, f1.w);
            }
        } else {
            const u32* Ab = (const u32*)Av;
            #pragma unroll
            for (int s = 0; s < 4; s++)
                xb[s] = *(const uint4*)(Ab + (long long)row * 64 + s * 16 + q * 4);
        }
    } else {
        xb[0] = xb[1] = xb[2] = xb[3] = make_uint4(0u, 0u, 0u, 0u);
    }

    float d = 1.0f;
    if (dis && live) d = dis[row];
    long long gbase = (gsrc && live) ? (long long)gidx[row] * 64 : 0;

    #pragma unroll
    for (int t = 0; t < 8; t++) {
        f32x4 acc = {0.f, 0.f, 0.f, 0.f};
        #pragma unroll
        for (int s = 0; s < 4; s++) {
            uint4 wa = *(const uint4*)&WL[((t * 4 + s) * 64 + lane) * 4];
            acc = __builtin_amdgcn_mfma_f32_16x16x32_bf16(asbf(wa), asbf(xb[s]), acc, 0, 0, 0);
        }
        if (live) {
            float v0 = acc[0], v1 = acc[1], v2 = acc[2], v3 = acc[3];
            int cbase = t * 16 + q * 4;
            if (gsrc) {
                uint2 g = *(const uint2*)(gsrc + gbase + (cbase >> 1));
                v0 += bl(g.x); v1 += bh(g.x);
                v2 += bl(g.y); v3 += bh(g.y);
            }
            if (pool) {
                float4 bb = *(const float4*)(bias + cbase);
                float4 sc = *(const float4*)(bnscale + cbase);
                float4 sh = *(const float4*)(bnshift + cbase);
                v0 = fmaxf(fmaxf(v0 + bb.x, 0.f) * sc.x + sh.x, 0.f);
                v1 = fmaxf(fmaxf(v1 + bb.y, 0.f) * sc.y + sh.y, 0.f);
                v2 = fmaxf(fmaxf(v2 + bb.z, 0.f) * sc.z + sh.z, 0.f);
                v3 = fmaxf(fmaxf(v3 + bb.w, 0.f) * sc.w + sh.w, 0.f);
            }
            v0 *= d; v1 *= d; v2 *= d; v3 *= d;
            uint2 st;
            st.x = pack2(v0, v1);
            st.y = pack2(v2, v3);
            *(uint2*)(out + (long long)row * 64 + (cbase >> 1)) = st;
        }
    }
}

// ---------------- matmul K=128, N=10; bf16 A, fp32 W, fp32 out ----------------
__global__ __launch_bounds__(256) void mm10_kernel(
    const u32* __restrict__ A, const float* __restrict__ W,
    float* __restrict__ out, int M)
{
    __shared__ float Ws[128 * 10];
    for (int i = threadIdx.x; i < 1280; i += 256) Ws[i] = W[i];
    __syncthreads();
    int row = blockIdx.x * blockDim.x + threadIdx.x;
    if (row >= M) return;
    const uint4* a = (const uint4*)(A + (long long)row * 64);
    float acc[10] = {0, 0, 0, 0, 0, 0, 0, 0, 0, 0};
    #pragma unroll 4
    for (int i = 0; i < 16; i++) {
        uint4 av = a[i];
        int k = i * 8;
        float f[8] = { bl(av.x), bh(av.x), bl(av.y), bh(av.y),
                       bl(av.z), bh(av.z), bl(av.w), bh(av.w) };
        #pragma unroll
        for (int j = 0; j < 8; j++) {
            #pragma unroll
            for (int cc = 0; cc < 10; cc++)
                acc[cc] += f[j] * Ws[(k + j) * 10 + cc];
        }
    }
    #pragma unroll
    for (int cc = 0; cc < 10; cc++) out[(long long)row * 10 + cc] = acc[cc];
}

// mm10 variant: + gather gsrc fp32 rows, * dis, output bf16-packed stride-8 rows
__global__ __launch_bounds__(256) void mm10p_kernel(
    const u32* __restrict__ A, const float* __restrict__ W,
    u32* __restrict__ outp, int M,
    const float* __restrict__ dis,
    const float* __restrict__ gsrc, const int* __restrict__ gidx)
{
    __shared__ float Ws[128 * 10];
    for (int i = threadIdx.x; i < 1280; i += 256) Ws[i] = W[i];
    __syncthreads();
    int row = blockIdx.x * blockDim.x + threadIdx.x;
    if (row >= M) return;
    const uint4* a = (const uint4*)(A + (long long)row * 64);
    float acc[10] = {0, 0, 0, 0, 0, 0, 0, 0, 0, 0};
    #pragma unroll 4
    for (int i = 0; i < 16; i++) {
        uint4 av = a[i];
        int k = i * 8;
        float f[8] = { bl(av.x), bh(av.x), bl(av.y), bh(av.y),
                       bl(av.z), bh(av.z), bl(av.w), bh(av.w) };
        #pragma unroll
        for (int j = 0; j < 8; j++) {
            #pragma unroll
            for (int cc = 0; cc < 10; cc++)
                acc[cc] += f[j] * Ws[(k + j) * 10 + cc];
        }
    }
    float d = dis[row];
    const float* g = gsrc + (long long)gidx[row] * 10;
    long long base = (long long)row * 8;
    #pragma unroll
    for (int j = 0; j < 5; j++) {
        float v0 = (acc[2 * j] + g[2 * j]) * d;
        float v1 = (acc[2 * j + 1] + g[2 * j + 1]) * d;
        outp[base + j] = pack2(v0, v1);
    }
}

// ---------------- launcher ----------------

extern "C" void kernel_launch(void* const* d_in, const int* in_sizes, int n_in,
                              void* d_out, int out_size, void* d_ws, size_t ws_size,
                              hipStream_t stream) {
    const float* x       = (const float*)d_in[0];
    const int*   ei0     = (const int*)d_in[1];
    const int*   ei1     = (const int*)d_in[2];
    const int*   ei2     = (const int*)d_in[3];
    const int*   parent1 = (const int*)d_in[4];
    const int*   parent2 = (const int*)d_in[5];
    const float* W0 = (const float*)d_in[6];
    const float* b0 = (const float*)d_in[7];
    const float* W1 = (const float*)d_in[8];
    const float* b1 = (const float*)d_in[9];
    const float* W2 = (const float*)d_in[10];
    const float* b2 = (const float*)d_in[11];
    const float* W3 = (const float*)d_in[12];
    const float* b3 = (const float*)d_in[13];
    const float* W4 = (const float*)d_in[14];
    const float* b4 = (const float*)d_in[15];
    const float* pW = (const float*)d_in[16];
    const float* pb = (const float*)d_in[17];
    const float* pg = (const float*)d_in[18];
    const float* pbeta = (const float*)d_in[19];
    const float* pmean = (const float*)d_in[20];
    const float* pvar  = (const float*)d_in[21];
    float* out = (float*)d_out;

    char* ws = (char*)d_ws;
    size_t off = 0;
    auto alloc = [&](size_t nbytes) -> char* {
        char* p = ws + off;
        off += ((nbytes + 255) / 256) * 256;
        return p;
    };
    // fp32 buffers
    float* dis0 = (float*)alloc(N0 * 4);
    float* dis1 = (float*)alloc(N1 * 4);
    float* dis2 = (float*)alloc(N2 * 4);
    float* bnscale = (float*)alloc(4 * HDIM * 4);
    float* bnshift = (float*)alloc(4 * HDIM * 4);
    float* W1b = (float*)alloc((size_t)N1 * 10 * 4);
    // bf16-packed feature buffers (64 u32 per 128-wide row)
    u32* Y   = (u32*)alloc((size_t)N0 * 64 * 4);
    u32* H0  = (u32*)alloc((size_t)N0 * 64 * 4);
    u32* H1  = (u32*)alloc((size_t)N1 * 64 * 4);
    u32* P   = (u32*)alloc((size_t)N1 * 64 * 4);
    u32* X1  = (u32*)alloc((size_t)N1 * 64 * 4);
    u32* HU1 = (u32*)alloc((size_t)N1 * 64 * 4);
    u32* U1  = (u32*)alloc((size_t)N1 * 64 * 4);
    u32* X2  = (u32*)alloc((size_t)N2 * 64 * 4);
    u32* H2  = (u32*)alloc((size_t)N2 * 64 * 4);
    u32* U2  = (u32*)alloc((size_t)N2 * 64 * 4);
    u32* V2  = (u32*)alloc((size_t)N2 * 64 * 4);
    u32* Y4p = (u32*)alloc((size_t)N0 * 8 * 4);   // bf16 stride-8 rows (32 B)
    // int buffers
    int* cntBase = (int*)alloc((size_t)OFFT * 4);
    int* rp0 = (int*)alloc((N0 + 1) * 4);
    int* rp1 = (int*)alloc((N1 + 1) * 4);
    int* rp2 = (int*)alloc((N2 + 1) * 4);
    int* pp1 = (int*)alloc((N1 + 1) * 4);
    int* pp2 = (int*)alloc((N2 + 1) * 4);
    int* rankB = (int*)alloc((size_t)S4 * 4);
    int* src0   = (int*)alloc((size_t)E0C * 4);
    int* src1   = (int*)alloc((size_t)E1C * 4);
    int* src2   = (int*)alloc((size_t)E2C * 4);
    int* child1 = (int*)alloc((size_t)N0 * 4);
    int* child2 = (int*)alloc((size_t)N1 * 4);
    // scan scratch
    int* Sarr   = (int*)alloc((size_t)(OFFT + 1) * 4);
    int* bsum   = (int*)alloc(NBLK * 4);
    int* totalb = (int*)alloc(4);

    const int B = 256;
    auto G = [](long long t) { return (unsigned)((t + 255) / 256); };
    auto G64 = [](long long m) { return (unsigned)((m + 63) / 64); };

    // ---- CSR build ----
    (void)hipMemsetAsync(cntBase, 0, (size_t)OFFT * 4, stream);
    count_all_kernel<<<G(TQ), B, 0, stream>>>(
        ei0 + E0C, ei1 + E1C, ei2 + E2C, parent1, parent2, cntBase, rankB);
    scan_k1<<<NBLK, B, 0, stream>>>(cntBase, bsum, OFFT);
    scan_k2<<<1, B, 0, stream>>>(bsum, totalb, NBLK);
    scan_k3<<<NBLK, B, 0, stream>>>(cntBase, bsum, totalb, Sarr, OFFT);
    csr_fixup_kernel<<<G(OFFT), B, 0, stream>>>(
        Sarr, cntBase, rp0, dis0, rp1, dis1, rp2, dis2, pp1, pp2);
    fill_all_kernel<<<G(TQ), B, 0, stream>>>(
        ei0, ei0 + E0C, ei1, ei1 + E1C, ei2, ei2 + E2C, parent1, parent2,
        rankB, rp0, rp1, rp2, pp1, pp2,
        src0, src1, src2, child1, child2);
    bn_pre_kernel<<<2, B, 0, stream>>>(pg, pbeta, pmean, pvar, bnscale, bnshift);

    // ---- gcn0: h0 = relu(gcn(x, ei0, W0, b0));  A = fp32 x staged directly ----
    mm128_kernel<<<G64(N0), B, 0, stream>>>(
        x, W0, Y, N0, dis0, nullptr, nullptr, nullptr, nullptr, nullptr, 0, 1);
    gather128_kernel<<<G((long long)N0 * 64), B, 0, stream>>>(rp0, src0, Y, dis0, b0, H0, N0);

    // ---- pool1 ----
    gatherP_kernel<<<G((long long)N1 * 64), B, 0, stream>>>(pp1, child1, H0, P, N1);
    mm128_kernel<<<G64(N1), B, 0, stream>>>(
        P, pW, X1, N1, nullptr, nullptr, nullptr, pb, bnscale, bnshift, 1, 0);

    // ---- gcn1 ----
    mm128_kernel<<<G64(N1), B, 0, stream>>>(
        X1, W1, Y, N1, dis1, nullptr, nullptr, nullptr, nullptr, nullptr, 0, 0);
    gather128_kernel<<<G((long long)N1 * 64), B, 0, stream>>>(rp1, src1, Y, dis1, b1, H1, N1);

    // ---- pool2 ----
    gatherP_kernel<<<G((long long)N2 * 64), B, 0, stream>>>(pp2, child2, H1, P, N2);
    mm128_kernel<<<G64(N2), B, 0, stream>>>(
        P, pW + 128 * 128, X2, N2, nullptr, nullptr, nullptr, pb + 128, bnscale + 128, bnshift + 128, 1, 0);

    // ---- gcn2 ----
    mm128_kernel<<<G64(N2), B, 0, stream>>>(
        X2, W2, Y, N2, dis2, nullptr, nullptr, nullptr, nullptr, nullptr, 0, 0);
    gather128_kernel<<<G((long long)N2 * 64), B, 0, stream>>>(rp2, src2, Y, dis2, b2, H2, N2);

    // ---- up level 2 ----
    mm128_kernel<<<G64(N2), B, 0, stream>>>(
        H2, pW + 2 * 128 * 128, U2, N2, nullptr, nullptr, nullptr, pb + 256, bnscale + 256, bnshift + 256, 1, 0);
    mm128_kernel<<<G64(N2), B, 0, stream>>>(
        U2, W3, V2, N2, nullptr, nullptr, nullptr, nullptr, nullptr, nullptr, 0, 0);

    // ---- gcn3 ----
    mm128_kernel<<<G64(N1), B, 0, stream>>>(
        H1, W3 + 128 * 128, Y, N1, dis1, V2, parent2, nullptr, nullptr, nullptr, 0, 0);
    gather128_kernel<<<G((long long)N1 * 64), B, 0, stream>>>(rp1, src1, Y, dis1, b3, HU1, N1);

    // ---- up level 1 ----
    mm128_kernel<<<G64(N1), B, 0, stream>>>(
        HU1, pW + 3 * 128 * 128, U1, N1, nullptr, nullptr, nullptr, pb + 384, bnscale + 384, bnshift + 384, 1, 0);
    mm10_kernel<<<G(N1), B, 0, stream>>>(U1, W4, W1b, N1);

    // ---- gcn4: y4p = bf16(dis0 * (w1b[parent1] + h0 @ W4_bot)); gather + log_softmax ----
    mm10p_kernel<<<G(N0), B, 0, stream>>>(H0, W4 + 128 * 10, Y4p, N0, dis0, W1b, parent1);
    gather10_lsm_kernel<<<G(N0), B, 0, stream>>>(rp0, src0, Y4p, dis0, b4, out, N0);
}

// Round 12
// 474.110 us; speedup vs baseline: 1.1173x; 1.1173x over previous
//
#include <hip/hip_runtime.h>
#include <math.h>

#define N0 100000
#define N1 20000
#define N2 4000
#define HDIM 128
#define E0C 1600000
#define E1C 320000
#define E2C 64000
#define EPSBN 1e-5f

typedef unsigned int u32;
typedef float f32x4 __attribute__((ext_vector_type(4)));
typedef short bf16x8 __attribute__((ext_vector_type(8)));

union FragU { uint4 u; bf16x8 h; };
__device__ __forceinline__ bf16x8 asbf(uint4 v) { FragU x; x.u = v; return x.h; }

__device__ __forceinline__ float bl(u32 p) { return __uint_as_float(p << 16); }
__device__ __forceinline__ float bh(u32 p) { return __uint_as_float(p & 0xFFFF0000u); }
__device__ __forceinline__ u32 pack2(float a, float b) {
    u32 ua = __float_as_uint(a), ub = __float_as_uint(b);
    ua = (ua + 0x7FFFu + ((ua >> 16) & 1u)) >> 16;
    ub = (ub + 0x7FFFu + ((ub >> 16) & 1u)) >> 16;
    return ua | (ub << 16);
}

// concatenated destination space
#define OFF0 0
#define OFF1 (N0)
#define OFF2 (N0 + N1)
#define OFF3 (N0 + N1 + N2)
#define OFF4 (N0 + N1 + N2 + N1)
#define OFFT (N0 + N1 + N2 + N1 + N2)        // 148000

// concatenated work items (edges + parent links)
#define S0 (E0C)
#define S1 (E0C + E1C)
#define S2 (E0C + E1C + E2C)
#define S3 (E0C + E1C + E2C + N0)
#define S4 (E0C + E1C + E2C + N0 + N1)       // 2,104,000

// counting-sort geometry
#define NBUCK ((OFFT + 1023) / 1024)         // 145 coarse buckets (1024 dests each)
#define ITEMS_PER_BLK 4096
#define NBA ((S4 + ITEMS_PER_BLK - 1) / ITEMS_PER_BLK)   // 514 blocks
#define BH_N (NBUCK * NBA)                   // 74,530 blockHist entries
#define NBLK2 ((BH_N + 1023) / 1024)         // 73 scan blocks

// ---------------- CSR build (LDS counting sort, zero global atomics) ----------------

__device__ __forceinline__ void item_full(int g,
    const int* __restrict__ ei0r, const int* __restrict__ ei0c,
    const int* __restrict__ ei1r, const int* __restrict__ ei1c,
    const int* __restrict__ ei2r, const int* __restrict__ ei2c,
    const int* __restrict__ p1, const int* __restrict__ p2,
    int& concat, int& payload)
{
    if (g < S0)      { concat = ei0c[g];             payload = ei0r[g]; }
    else if (g < S1) { int i = g - S0; concat = OFF1 + ei1c[i]; payload = ei1r[i]; }
    else if (g < S2) { int i = g - S1; concat = OFF2 + ei2c[i]; payload = ei2r[i]; }
    else if (g < S3) { int i = g - S2; concat = OFF3 + p1[i];   payload = i; }
    else             { int i = g - S3; concat = OFF4 + p2[i];   payload = i; }
}

// A1: per-block coarse histogram into LDS, write bucket-major blockHist[b*NBA + blk]
__global__ __launch_bounds__(256) void binhist_kernel(
    const int* __restrict__ ei0r, const int* __restrict__ ei0c,
    const int* __restrict__ ei1r, const int* __restrict__ ei1c,
    const int* __restrict__ ei2r, const int* __restrict__ ei2c,
    const int* __restrict__ p1, const int* __restrict__ p2,
    int* __restrict__ blockHist)
{
    __shared__ int hist[NBUCK];
    int tid = threadIdx.x, blk = blockIdx.x;
    for (int i = tid; i < NBUCK; i += 256) hist[i] = 0;
    __syncthreads();
    int base = blk * ITEMS_PER_BLK;
    #pragma unroll
    for (int k = 0; k < 16; k++) {
        int g = base + k * 256 + tid;
        if (g < S4) {
            int c, p;
            item_full(g, ei0r, ei0c, ei1r, ei1c, ei2r, ei2c, p1, p2, c, p);
            atomicAdd(&hist[c >> 10], 1);
        }
    }
    __syncthreads();
    for (int b = tid; b < NBUCK; b += 256) blockHist[b * NBA + blk] = hist[b];
}

// generic 3-phase scan (reused for blockHist)
__global__ __launch_bounds__(256) void scan_k1(const int* __restrict__ c, int* __restrict__ bsum, int n) {
    int t = threadIdx.x;
    int base = blockIdx.x * 1024 + t * 4;
    int s = 0;
    #pragma unroll
    for (int j = 0; j < 4; j++) {
        int idx = base + j;
        if (idx < n) s += c[idx];
    }
    #pragma unroll
    for (int o = 32; o > 0; o >>= 1) s += __shfl_down(s, o, 64);
    __shared__ int ws[4];
    if ((t & 63) == 0) ws[t >> 6] = s;
    __syncthreads();
    if (t == 0) bsum[blockIdx.x] = ws[0] + ws[1] + ws[2] + ws[3];
}

__global__ __launch_bounds__(256) void scan_k2(int* __restrict__ bsum, int* __restrict__ totalOut, int nb) {
    int t = threadIdx.x;
    int v = (t < nb) ? bsum[t] : 0;
    __shared__ int ts[256];
    ts[t] = v;
    __syncthreads();
    for (int o = 1; o < 256; o <<= 1) {
        int u = (t >= o) ? ts[t - o] : 0;
        __syncthreads();
        ts[t] += u;
        __syncthreads();
    }
    if (t < nb) bsum[t] = ts[t] - v;
    if (t == nb - 1) *totalOut = ts[t];
}

__global__ __launch_bounds__(256) void scan_k3(const int* __restrict__ c, const int* __restrict__ bsum,
                                               const int* __restrict__ total,
                                               int* __restrict__ S, int n) {
    int t = threadIdx.x;
    int base = blockIdx.x * 1024 + t * 4;
    int v[4];
    #pragma unroll
    for (int j = 0; j < 4; j++) v[j] = (base + j < n) ? c[base + j] : 0;
    int tsum = v[0] + v[1] + v[2] + v[3];
    __shared__ int ts[256];
    ts[t] = tsum;
    __syncthreads();
    for (int o = 1; o < 256; o <<= 1) {
        int u = (t >= o) ? ts[t - o] : 0;
        __syncthreads();
        ts[t] += u;
        __syncthreads();
    }
    int run = bsum[blockIdx.x] + ts[t] - tsum;
    #pragma unroll
    for (int j = 0; j < 4; j++) {
        if (base + j < n) { S[base + j] = run; run += v[j]; }
    }
    if (blockIdx.x == 0 && t == 0) S[n] = *total;
}

// A3: bin items into bucket-contiguous (dest,payload) pairs using LDS cursors
__global__ __launch_bounds__(256) void binfill_kernel(
    const int* __restrict__ ei0r, const int* __restrict__ ei0c,
    const int* __restrict__ ei1r, const int* __restrict__ ei1c,
    const int* __restrict__ ei2r, const int* __restrict__ ei2c,
    const int* __restrict__ p1, const int* __restrict__ p2,
    const int* __restrict__ OfsAbs, uint2* __restrict__ binPair)
{
    __shared__ int cur[NBUCK];
    int tid = threadIdx.x, blk = blockIdx.x;
    for (int i = tid; i < NBUCK; i += 256) cur[i] = OfsAbs[i * NBA + blk];
    __syncthreads();
    int base = blk * ITEMS_PER_BLK;
    #pragma unroll
    for (int k = 0; k < 16; k++) {
        int g = base + k * 256 + tid;
        if (g < S4) {
            int c, p;
            item_full(g, ei0r, ei0c, ei1r, ei1c, ei2r, ei2c, p1, p2, c, p);
            int pos = atomicAdd(&cur[c >> 10], 1);
            binPair[pos] = make_uint2((u32)c, (u32)p);
        }
    }
}

// B: per-bucket fine counting sort: counts -> LDS scan -> rpAll/dis -> scatter payloads
__global__ __launch_bounds__(256) void bucket_build_kernel(
    const uint2* __restrict__ binPair, const int* __restrict__ OfsAbs,
    int* __restrict__ rpAll, int* __restrict__ srcU,
    float* __restrict__ dis0, float* __restrict__ dis1, float* __restrict__ dis2)
{
    __shared__ int cnt_l[1024];
    __shared__ int rp_l[1024];
    __shared__ int ts[256];
    int b = blockIdx.x, tid = threadIdx.x;
    int start = OfsAbs[b * NBA];
    int end = (b + 1 < NBUCK) ? OfsAbs[(b + 1) * NBA] : S4;
    int d0 = b << 10;
    int nd = OFFT - d0; if (nd > 1024) nd = 1024;

    for (int i = tid; i < 1024; i += 256) cnt_l[i] = 0;
    __syncthreads();
    for (int i = start + tid; i < end; i += 256) {
        uint2 e = binPair[i];
        atomicAdd(&cnt_l[(int)e.x - d0], 1);
    }
    __syncthreads();
    // exclusive scan of cnt_l -> rp_l
    int bi = tid * 4;
    int v0 = cnt_l[bi], v1 = cnt_l[bi + 1], v2 = cnt_l[bi + 2], v3 = cnt_l[bi + 3];
    int tsum = v0 + v1 + v2 + v3;
    ts[tid] = tsum;
    __syncthreads();
    for (int o = 1; o < 256; o <<= 1) {
        int u = (tid >= o) ? ts[tid - o] : 0;
        __syncthreads();
        ts[tid] += u;
        __syncthreads();
    }
    int run = ts[tid] - tsum;
    rp_l[bi] = run;
    rp_l[bi + 1] = run + v0;
    rp_l[bi + 2] = run + v0 + v1;
    rp_l[bi + 3] = run + v0 + v1 + v2;
    __syncthreads();
    // write rpAll (absolute) + dis (fused)
    for (int j = tid; j < nd; j += 256) {
        int g = d0 + j;
        rpAll[g] = start + rp_l[j];
        int c = cnt_l[j];
        float dv = rsqrtf((float)(c + 1));
        if (g < OFF1) dis0[g] = dv;
        else if (g < OFF2) dis1[g - OFF1] = dv;
        else if (g < OFF3) dis2[g - OFF2] = dv;
    }
    if (b == NBUCK - 1 && tid == 0) rpAll[OFFT] = S4;
    __syncthreads();
    // scatter payloads to final positions (rp_l doubles as cursor)
    for (int i = start + tid; i < end; i += 256) {
        uint2 e = binPair[i];
        int pos = start + atomicAdd(&rp_l[(int)e.x - d0], 1);
        srcU[pos] = (int)e.y;
    }
}

__global__ void bn_pre_kernel(const float* __restrict__ g, const float* __restrict__ beta,
                              const float* __restrict__ mean, const float* __restrict__ var,
                              float* __restrict__ scale, float* __restrict__ shift) {
    int i = blockIdx.x * blockDim.x + threadIdx.x;
    if (i < 4 * HDIM) {
        float s = g[i] * rsqrtf(var[i] + EPSBN);
        scale[i] = s;
        shift[i] = beta[i] - mean[i] * s;
    }
}

// ---------------- gather kernels (bf16 features, fp32 accumulate) ----------------
// rp is absolute into srcU (pass rpAll + level offset)

__global__ __launch_bounds__(256) void gather128_kernel(
    const int* __restrict__ rp, const int* __restrict__ srcl,
    const u32* __restrict__ y, const float* __restrict__ dis,
    const float* __restrict__ bias, u32* __restrict__ h, int n)
{
    int wid = (int)((blockIdx.x * 256 + threadIdx.x) >> 6);
    int lane = threadIdx.x & 63;
    if (wid >= n) return;
    u32 self = y[(long long)wid * 64 + lane];
    float ax = bl(self), ay = bh(self);
    int e = rp[wid], e1 = rp[wid + 1];
    for (; e + 3 < e1; e += 4) {
        int s0 = srcl[e], s1 = srcl[e + 1], s2 = srcl[e + 2], s3 = srcl[e + 3];
        u32 p0 = y[(long long)s0 * 64 + lane];
        u32 p1 = y[(long long)s1 * 64 + lane];
        u32 p2 = y[(long long)s2 * 64 + lane];
        u32 p3 = y[(long long)s3 * 64 + lane];
        ax += (bl(p0) + bl(p1)) + (bl(p2) + bl(p3));
        ay += (bh(p0) + bh(p1)) + (bh(p2) + bh(p3));
    }
    if (e + 1 < e1) {
        u32 p0 = y[(long long)srcl[e] * 64 + lane];
        u32 p1 = y[(long long)srcl[e + 1] * 64 + lane];
        ax += bl(p0) + bl(p1);
        ay += bh(p0) + bh(p1);
        e += 2;
    }
    if (e < e1) {
        u32 p = y[(long long)srcl[e] * 64 + lane];
        ax += bl(p); ay += bh(p);
    }
    float d = dis[wid];
    float2 b = ((const float2*)bias)[lane];
    float r0 = fmaxf(fmaf(d, ax, b.x), 0.f);
    float r1 = fmaxf(fmaf(d, ay, b.y), 0.f);
    h[(long long)wid * 64 + lane] = pack2(r0, r1);
}

__global__ __launch_bounds__(256) void gatherP_kernel(
    const int* __restrict__ pp, const int* __restrict__ childl,
    const u32* __restrict__ h, u32* __restrict__ p, int n)
{
    int wid = (int)((blockIdx.x * 256 + threadIdx.x) >> 6);
    int lane = threadIdx.x & 63;
    if (wid >= n) return;
    float ax = 0.f, ay = 0.f;
    int e = pp[wid], e1 = pp[wid + 1];
    for (; e + 3 < e1; e += 4) {
        int s0 = childl[e], s1 = childl[e + 1], s2 = childl[e + 2], s3 = childl[e + 3];
        u32 p0 = h[(long long)s0 * 64 + lane];
        u32 p1 = h[(long long)s1 * 64 + lane];
        u32 p2 = h[(long long)s2 * 64 + lane];
        u32 p3 = h[(long long)s3 * 64 + lane];
        ax += (bl(p0) + bl(p1)) + (bl(p2) + bl(p3));
        ay += (bh(p0) + bh(p1)) + (bh(p2) + bh(p3));
    }
    if (e + 1 < e1) {
        u32 p0 = h[(long long)childl[e] * 64 + lane];
        u32 p1 = h[(long long)childl[e + 1] * 64 + lane];
        ax += bl(p0) + bl(p1);
        ay += bh(p0) + bh(p1);
        e += 2;
    }
    if (e < e1) {
        u32 q = h[(long long)childl[e] * 64 + lane];
        ax += bl(q); ay += bh(q);
    }
    p[(long long)wid * 64 + lane] = pack2(ax, ay);
}

__global__ __launch_bounds__(256) void gather10_lsm_kernel(
    const int* __restrict__ rp, const int* __restrict__ srcl,
    const u32* __restrict__ y4, const float* __restrict__ dis,
    const float* __restrict__ bias, float* __restrict__ out, int n)
{
    int c = blockIdx.x * blockDim.x + threadIdx.x;
    if (c >= n) return;
    float acc[10];
    {
        long long base = (long long)c * 8;
        uint4 q = *(const uint4*)(y4 + base);
        u32 q4 = y4[base + 4];
        acc[0] = bl(q.x); acc[1] = bh(q.x);
        acc[2] = bl(q.y); acc[3] = bh(q.y);
        acc[4] = bl(q.z); acc[5] = bh(q.z);
        acc[6] = bl(q.w); acc[7] = bh(q.w);
        acc[8] = bl(q4);  acc[9] = bh(q4);
    }
    int e = rp[c], e1 = rp[c + 1];
    for (; e + 1 < e1; e += 2) {
        long long bA = (long long)srcl[e] * 8;
        long long bB = (long long)srcl[e + 1] * 8;
        uint4 qa = *(const uint4*)(y4 + bA);
        u32 qa4 = y4[bA + 4];
        uint4 qb = *(const uint4*)(y4 + bB);
        u32 qb4 = y4[bB + 4];
        acc[0] += bl(qa.x) + bl(qb.x); acc[1] += bh(qa.x) + bh(qb.x);
        acc[2] += bl(qa.y) + bl(qb.y); acc[3] += bh(qa.y) + bh(qb.y);
        acc[4] += bl(qa.z) + bl(qb.z); acc[5] += bh(qa.z) + bh(qb.z);
        acc[6] += bl(qa.w) + bl(qb.w); acc[7] += bh(qa.w) + bh(qb.w);
        acc[8] += bl(qa4) + bl(qb4);   acc[9] += bh(qa4) + bh(qb4);
    }
    if (e < e1) {
        long long bA = (long long)srcl[e] * 8;
        uint4 qa = *(const uint4*)(y4 + bA);
        u32 qa4 = y4[bA + 4];
        acc[0] += bl(qa.x); acc[1] += bh(qa.x);
        acc[2] += bl(qa.y); acc[3] += bh(qa.y);
        acc[4] += bl(qa.z); acc[5] += bh(qa.z);
        acc[6] += bl(qa.w); acc[7] += bh(qa.w);
        acc[8] += bl(qa4);  acc[9] += bh(qa4);
    }
    float d = dis[c];
    float m = -1e30f;
    #pragma unroll
    for (int k = 0; k < 10; k++) {
        acc[k] = fmaf(d, acc[k], bias[k]);
        m = fmaxf(m, acc[k]);
    }
    float s = 0.f;
    #pragma unroll
    for (int k = 0; k < 10; k++) s += expf(acc[k] - m);
    float ls = logf(s);
    #pragma unroll
    for (int k = 0; k < 10; k++) out[(long long)c * 10 + k] = acc[k] - m - ls;
}

// ---------------- MFMA matmul K=128, N=128 ----------------
__global__ __launch_bounds__(256) void mm128_kernel(
    const void* __restrict__ Av, const float* __restrict__ W,
    u32* __restrict__ out, int M,
    const float* __restrict__ dis,
    const u32* __restrict__ gsrc, const int* __restrict__ gidx,
    const float* __restrict__ bias,
    const float* __restrict__ bnscale, const float* __restrict__ bnshift,
    int pool, int afp32)
{
    __shared__ u32 WL[8192];   // [t=8][s=4][lane=64][i=4]
    int tid = threadIdx.x;

    #pragma unroll
    for (int it = 0; it < 32; it++) {
        int flat = it * 256 + tid;
        int i = flat & 3;
        int ln = (flat >> 2) & 63;
        int s = (flat >> 8) & 3;
        int t = flat >> 10;
        int mm = ln & 15, qq = ln >> 4;
        int k0 = s * 32 + qq * 8 + 2 * i;
        int col = t * 16 + mm;
        WL[flat] = pack2(W[k0 * 128 + col], W[(k0 + 1) * 128 + col]);
    }
    __syncthreads();

    int lane = tid & 63;
    int w = tid >> 6;
    int m = lane & 15, q = lane >> 4;
    int row = blockIdx.x * 64 + w * 16 + m;
    bool live = (row < M);

    uint4 xb[4];
    if (live) {
        if (afp32) {
            const float* Af = (const float*)Av;
            #pragma unroll
            for (int s = 0; s < 4; s++) {
                const float4* p = (const float4*)(Af + (long long)row * 128 + s * 32 + q * 8);
                float4 f0 = p[0], f1 = p[1];
                xb[s].x = pack2(f0.x, f0.y);
                xb[s].y = pack2(f0.z, f0.w);
                xb[s].z = pack2(f1.x, f1.y);
                xb[s].w = pack2(f1.z, f1.w);
            }
        } else {
            const u32* Ab = (const u32*)Av;
            #pragma unroll
            for (int s = 0; s < 4; s++)
                xb[s] = *(const uint4*)(Ab + (long long)row * 64 + s * 16 + q * 4);
        }
    } else {
        xb[0] = xb[1] = xb[2] = xb[3] = make_uint4(0u, 0u, 0u, 0u);
    }

    float d = 1.0f;
    if (dis && live) d = dis[row];
    long long gbase = (gsrc && live) ? (long long)gidx[row] * 64 : 0;

    #pragma unroll
    for (int t = 0; t < 8; t++) {
        f32x4 acc = {0.f, 0.f, 0.f, 0.f};
        #pragma unroll
        for (int s = 0; s < 4; s++) {
            uint4 wa = *(const uint4*)&WL[((t * 4 + s) * 64 + lane) * 4];
            acc = __builtin_amdgcn_mfma_f32_16x16x32_bf16(asbf(wa), asbf(xb[s]), acc, 0, 0, 0);
        }
        if (live) {
            float v0 = acc[0], v1 = acc[1], v2 = acc[2], v3 = acc[3];
            int cbase = t * 16 + q * 4;
            if (gsrc) {
                uint2 g = *(const uint2*)(gsrc + gbase + (cbase >> 1));
                v0 += bl(g.x); v1 += bh(g.x);
                v2 += bl(g.y); v3 += bh(g.y);
            }
            if (pool) {
                float4 bb = *(const float4*)(bias + cbase);
                float4 sc = *(const float4*)(bnscale + cbase);
                float4 sh = *(const float4*)(bnshift + cbase);
                v0 = fmaxf(fmaxf(v0 + bb.x, 0.f) * sc.x + sh.x, 0.f);
                v1 = fmaxf(fmaxf(v1 + bb.y, 0.f) * sc.y + sh.y, 0.f);
                v2 = fmaxf(fmaxf(v2 + bb.z, 0.f) * sc.z + sh.z, 0.f);
                v3 = fmaxf(fmaxf(v3 + bb.w, 0.f) * sc.w + sh.w, 0.f);
            }
            v0 *= d; v1 *= d; v2 *= d; v3 *= d;
            uint2 st;
            st.x = pack2(v0, v1);
            st.y = pack2(v2, v3);
            *(uint2*)(out + (long long)row * 64 + (cbase >> 1)) = st;
        }
    }
}

// ---------------- matmul K=128, N=10; bf16 A, fp32 W, fp32 out ----------------
__global__ __launch_bounds__(256) void mm10_kernel(
    const u32* __restrict__ A, const float* __restrict__ W,
    float* __restrict__ out, int M)
{
    __shared__ float Ws[128 * 10];
    for (int i = threadIdx.x; i < 1280; i += 256) Ws[i] = W[i];
    __syncthreads();
    int row = blockIdx.x * blockDim.x + threadIdx.x;
    if (row >= M) return;
    const uint4* a = (const uint4*)(A + (long long)row * 64);
    float acc[10] = {0, 0, 0, 0, 0, 0, 0, 0, 0, 0};
    #pragma unroll 4
    for (int i = 0; i < 16; i++) {
        uint4 av = a[i];
        int k = i * 8;
        float f[8] = { bl(av.x), bh(av.x), bl(av.y), bh(av.y),
                       bl(av.z), bh(av.z), bl(av.w), bh(av.w) };
        #pragma unroll
        for (int j = 0; j < 8; j++) {
            #pragma unroll
            for (int cc = 0; cc < 10; cc++)
                acc[cc] += f[j] * Ws[(k + j) * 10 + cc];
        }
    }
    #pragma unroll
    for (int cc = 0; cc < 10; cc++) out[(long long)row * 10 + cc] = acc[cc];
}

__global__ __launch_bounds__(256) void mm10p_kernel(
    const u32* __restrict__ A, const float* __restrict__ W,
    u32* __restrict__ outp, int M,
    const float* __restrict__ dis,
    const float* __restrict__ gsrc, const int* __restrict__ gidx)
{
    __shared__ float Ws[128 * 10];
    for (int i = threadIdx.x; i < 1280; i += 256) Ws[i] = W[i];
    __syncthreads();
    int row = blockIdx.x * blockDim.x + threadIdx.x;
    if (row >= M) return;
    const uint4* a = (const uint4*)(A + (long long)row * 64);
    float acc[10] = {0, 0, 0, 0, 0, 0, 0, 0, 0, 0};
    #pragma unroll 4
    for (int i = 0; i < 16; i++) {
        uint4 av = a[i];
        int k = i * 8;
        float f[8] = { bl(av.x), bh(av.x), bl(av.y), bh(av.y),
                       bl(av.z), bh(av.z), bl(av.w), bh(av.w) };
        #pragma unroll
        for (int j = 0; j < 8; j++) {
            #pragma unroll
            for (int cc = 0; cc < 10; cc++)
                acc[cc] += f[j] * Ws[(k + j) * 10 + cc];
        }
    }
    float d = dis[row];
    const float* g = gsrc + (long long)gidx[row] * 10;
    long long base = (long long)row * 8;
    #pragma unroll
    for (int j = 0; j < 5; j++) {
        float v0 = (acc[2 * j] + g[2 * j]) * d;
        float v1 = (acc[2 * j + 1] + g[2 * j + 1]) * d;
        outp[base + j] = pack2(v0, v1);
    }
}

// ---------------- launcher ----------------

extern "C" void kernel_launch(void* const* d_in, const int* in_sizes, int n_in,
                              void* d_out, int out_size, void* d_ws, size_t ws_size,
                              hipStream_t stream) {
    const float* x       = (const float*)d_in[0];
    const int*   ei0     = (const int*)d_in[1];
    const int*   ei1     = (const int*)d_in[2];
    const int*   ei2     = (const int*)d_in[3];
    const int*   parent1 = (const int*)d_in[4];
    const int*   parent2 = (const int*)d_in[5];
    const float* W0 = (const float*)d_in[6];
    const float* b0 = (const float*)d_in[7];
    const float* W1 = (const float*)d_in[8];
    const float* b1 = (const float*)d_in[9];
    const float* W2 = (const float*)d_in[10];
    const float* b2 = (const float*)d_in[11];
    const float* W3 = (const float*)d_in[12];
    const float* b3 = (const float*)d_in[13];
    const float* W4 = (const float*)d_in[14];
    const float* b4 = (const float*)d_in[15];
    const float* pW = (const float*)d_in[16];
    const float* pb = (const float*)d_in[17];
    const float* pg = (const float*)d_in[18];
    const float* pbeta = (const float*)d_in[19];
    const float* pmean = (const float*)d_in[20];
    const float* pvar  = (const float*)d_in[21];
    float* out = (float*)d_out;

    char* ws = (char*)d_ws;
    size_t off = 0;
    auto alloc = [&](size_t nbytes) -> char* {
        char* p = ws + off;
        off += ((nbytes + 255) / 256) * 256;
        return p;
    };
    // fp32 buffers
    float* dis0 = (float*)alloc(N0 * 4);
    float* dis1 = (float*)alloc(N1 * 4);
    float* dis2 = (float*)alloc(N2 * 4);
    float* bnscale = (float*)alloc(4 * HDIM * 4);
    float* bnshift = (float*)alloc(4 * HDIM * 4);
    float* W1b = (float*)alloc((size_t)N1 * 10 * 4);
    // bf16-packed feature buffers
    u32* Y   = (u32*)alloc((size_t)N0 * 64 * 4);
    u32* H0  = (u32*)alloc((size_t)N0 * 64 * 4);
    u32* H1  = (u32*)alloc((size_t)N1 * 64 * 4);
    u32* P   = (u32*)alloc((size_t)N1 * 64 * 4);
    u32* X1  = (u32*)alloc((size_t)N1 * 64 * 4);
    u32* HU1 = (u32*)alloc((size_t)N1 * 64 * 4);
    u32* U1  = (u32*)alloc((size_t)N1 * 64 * 4);
    u32* X2  = (u32*)alloc((size_t)N2 * 64 * 4);
    u32* H2  = (u32*)alloc((size_t)N2 * 64 * 4);
    u32* U2  = (u32*)alloc((size_t)N2 * 64 * 4);
    u32* V2  = (u32*)alloc((size_t)N2 * 64 * 4);
    u32* Y4p = (u32*)alloc((size_t)N0 * 8 * 4);
    // CSR structures
    int* rpAll = (int*)alloc((size_t)(OFFT + 1) * 4);
    int* srcU  = (int*)alloc((size_t)S4 * 4);
    // counting-sort scratch
    int*   blockHist = (int*)alloc((size_t)BH_N * 4);
    int*   OfsAbs    = (int*)alloc((size_t)(BH_N + 1) * 4);
    uint2* binPair   = (uint2*)alloc((size_t)S4 * 8);
    int* bsum   = (int*)alloc(NBLK2 * 4);
    int* totalb = (int*)alloc(4);

    const int B = 256;
    auto G = [](long long t) { return (unsigned)((t + 255) / 256); };
    auto G64 = [](long long m) { return (unsigned)((m + 63) / 64); };

    // ---- CSR build (LDS counting sort, no global atomics) ----
    binhist_kernel<<<NBA, B, 0, stream>>>(
        ei0, ei0 + E0C, ei1, ei1 + E1C, ei2, ei2 + E2C, parent1, parent2, blockHist);
    scan_k1<<<NBLK2, B, 0, stream>>>(blockHist, bsum, BH_N);
    scan_k2<<<1, B, 0, stream>>>(bsum, totalb, NBLK2);
    scan_k3<<<NBLK2, B, 0, stream>>>(blockHist, bsum, totalb, OfsAbs, BH_N);
    binfill_kernel<<<NBA, B, 0, stream>>>(
        ei0, ei0 + E0C, ei1, ei1 + E1C, ei2, ei2 + E2C, parent1, parent2, OfsAbs, binPair);
    bucket_build_kernel<<<NBUCK, B, 0, stream>>>(
        binPair, OfsAbs, rpAll, srcU, dis0, dis1, dis2);
    bn_pre_kernel<<<2, B, 0, stream>>>(pg, pbeta, pmean, pvar, bnscale, bnshift);

    // ---- gcn0 ----
    mm128_kernel<<<G64(N0), B, 0, stream>>>(
        x, W0, Y, N0, dis0, nullptr, nullptr, nullptr, nullptr, nullptr, 0, 1);
    gather128_kernel<<<G((long long)N0 * 64), B, 0, stream>>>(rpAll + OFF0, srcU, Y, dis0, b0, H0, N0);

    // ---- pool1 ----
    gatherP_kernel<<<G((long long)N1 * 64), B, 0, stream>>>(rpAll + OFF3, srcU, H0, P, N1);
    mm128_kernel<<<G64(N1), B, 0, stream>>>(
        P, pW, X1, N1, nullptr, nullptr, nullptr, pb, bnscale, bnshift, 1, 0);

    // ---- gcn1 ----
    mm128_kernel<<<G64(N1), B, 0, stream>>>(
        X1, W1, Y, N1, dis1, nullptr, nullptr, nullptr, nullptr, nullptr, 0, 0);
    gather128_kernel<<<G((long long)N1 * 64), B, 0, stream>>>(rpAll + OFF1, srcU, Y, dis1, b1, H1, N1);

    // ---- pool2 ----
    gatherP_kernel<<<G((long long)N2 * 64), B, 0, stream>>>(rpAll + OFF4, srcU, H1, P, N2);
    mm128_kernel<<<G64(N2), B, 0, stream>>>(
        P, pW + 128 * 128, X2, N2, nullptr, nullptr, nullptr, pb + 128, bnscale + 128, bnshift + 128, 1, 0);

    // ---- gcn2 ----
    mm128_kernel<<<G64(N2), B, 0, stream>>>(
        X2, W2, Y, N2, dis2, nullptr, nullptr, nullptr, nullptr, nullptr, 0, 0);
    gather128_kernel<<<G((long long)N2 * 64), B, 0, stream>>>(rpAll + OFF2, srcU, Y, dis2, b2, H2, N2);

    // ---- up level 2 ----
    mm128_kernel<<<G64(N2), B, 0, stream>>>(
        H2, pW + 2 * 128 * 128, U2, N2, nullptr, nullptr, nullptr, pb + 256, bnscale + 256, bnshift + 256, 1, 0);
    mm128_kernel<<<G64(N2), B, 0, stream>>>(
        U2, W3, V2, N2, nullptr, nullptr, nullptr, nullptr, nullptr, nullptr, 0, 0);

    // ---- gcn3 ----
    mm128_kernel<<<G64(N1), B, 0, stream>>>(
        H1, W3 + 128 * 128, Y, N1, dis1, V2, parent2, nullptr, nullptr, nullptr, 0, 0);
    gather128_kernel<<<G((long long)N1 * 64), B, 0, stream>>>(rpAll + OFF1, srcU, Y, dis1, b3, HU1, N1);

    // ---- up level 1 ----
    mm128_kernel<<<G64(N1), B, 0, stream>>>(
        HU1, pW + 3 * 128 * 128, U1, N1, nullptr, nullptr, nullptr, pb + 384, bnscale + 384, bnshift + 384, 1, 0);
    mm10_kernel<<<G(N1), B, 0, stream>>>(U1, W4, W1b, N1);

    // ---- gcn4 ----
    mm10p_kernel<<<G(N0), B, 0, stream>>>(H0, W4 + 128 * 10, Y4p, N0, dis0, W1b, parent1);
    gather10_lsm_kernel<<<G(N0), B, 0, stream>>>(rpAll + OFF0, srcU, Y4p, dis0, b4, out, N0);
}

// Round 13
// 449.253 us; speedup vs baseline: 1.1791x; 1.0553x over previous
//
#include <hip/hip_runtime.h>
#include <math.h>

#define N0 100000
#define N1 20000
#define N2 4000
#define HDIM 128
#define E0C 1600000
#define E1C 320000
#define E2C 64000
#define EPSBN 1e-5f

typedef unsigned int u32;
typedef float f32x4 __attribute__((ext_vector_type(4)));
typedef short bf16x8 __attribute__((ext_vector_type(8)));

union FragU { uint4 u; bf16x8 h; };
__device__ __forceinline__ bf16x8 asbf(uint4 v) { FragU x; x.u = v; return x.h; }

__device__ __forceinline__ float bl(u32 p) { return __uint_as_float(p << 16); }
__device__ __forceinline__ float bh(u32 p) { return __uint_as_float(p & 0xFFFF0000u); }
__device__ __forceinline__ u32 pack2(float a, float b) {
    u32 ua = __float_as_uint(a), ub = __float_as_uint(b);
    ua = (ua + 0x7FFFu + ((ua >> 16) & 1u)) >> 16;
    ub = (ub + 0x7FFFu + ((ub >> 16) & 1u)) >> 16;
    return ua | (ub << 16);
}

// concatenated destination space
#define OFF0 0
#define OFF1 (N0)
#define OFF2 (N0 + N1)
#define OFF3 (N0 + N1 + N2)
#define OFF4 (N0 + N1 + N2 + N1)
#define OFFT (N0 + N1 + N2 + N1 + N2)        // 148000

// concatenated work items (edges + parent links)
#define S0 (E0C)
#define S1 (E0C + E1C)
#define S2 (E0C + E1C + E2C)
#define S3 (E0C + E1C + E2C + N0)
#define S4 (E0C + E1C + E2C + N0 + N1)       // 2,104,000

// counting-sort geometry
#define NBUCK ((OFFT + 1023) / 1024)         // 145 coarse buckets
#define ITEMS_PER_BLK 4096
#define NBA ((S4 + ITEMS_PER_BLK - 1) / ITEMS_PER_BLK)   // 514 blocks
#define BH_N (NBUCK * NBA)
#define NBLK2 ((BH_N + 1023) / 1024)

// ---------------- CSR build (LDS counting sort, zero global atomics) ----------------

__device__ __forceinline__ void item_full(int g,
    const int* __restrict__ ei0r, const int* __restrict__ ei0c,
    const int* __restrict__ ei1r, const int* __restrict__ ei1c,
    const int* __restrict__ ei2r, const int* __restrict__ ei2c,
    const int* __restrict__ p1, const int* __restrict__ p2,
    int& concat, int& payload)
{
    if (g < S0)      { concat = ei0c[g];             payload = ei0r[g]; }
    else if (g < S1) { int i = g - S0; concat = OFF1 + ei1c[i]; payload = ei1r[i]; }
    else if (g < S2) { int i = g - S1; concat = OFF2 + ei2c[i]; payload = ei2r[i]; }
    else if (g < S3) { int i = g - S2; concat = OFF3 + p1[i];   payload = i; }
    else             { int i = g - S3; concat = OFF4 + p2[i];   payload = i; }
}

// concat only — avoids loading payload arrays in the histogram pass
__device__ __forceinline__ int item_concat(int g,
    const int* __restrict__ ei0c, const int* __restrict__ ei1c, const int* __restrict__ ei2c,
    const int* __restrict__ p1, const int* __restrict__ p2)
{
    if (g < S0)      return ei0c[g];
    else if (g < S1) return OFF1 + ei1c[g - S0];
    else if (g < S2) return OFF2 + ei2c[g - S1];
    else if (g < S3) return OFF3 + p1[g - S2];
    else             return OFF4 + p2[g - S3];
}

// A1: per-block coarse histogram into LDS
__global__ __launch_bounds__(256) void binhist_kernel(
    const int* __restrict__ ei0c, const int* __restrict__ ei1c, const int* __restrict__ ei2c,
    const int* __restrict__ p1, const int* __restrict__ p2,
    int* __restrict__ blockHist)
{
    __shared__ int hist[NBUCK];
    int tid = threadIdx.x, blk = blockIdx.x;
    for (int i = tid; i < NBUCK; i += 256) hist[i] = 0;
    __syncthreads();
    int base = blk * ITEMS_PER_BLK;
    #pragma unroll
    for (int k = 0; k < 16; k++) {
        int g = base + k * 256 + tid;
        if (g < S4) {
            int c = item_concat(g, ei0c, ei1c, ei2c, p1, p2);
            atomicAdd(&hist[c >> 10], 1);
        }
    }
    __syncthreads();
    for (int b = tid; b < NBUCK; b += 256) blockHist[b * NBA + blk] = hist[b];
}

// generic 3-phase scan
__global__ __launch_bounds__(256) void scan_k1(const int* __restrict__ c, int* __restrict__ bsum, int n) {
    int t = threadIdx.x;
    int base = blockIdx.x * 1024 + t * 4;
    int s = 0;
    #pragma unroll
    for (int j = 0; j < 4; j++) {
        int idx = base + j;
        if (idx < n) s += c[idx];
    }
    #pragma unroll
    for (int o = 32; o > 0; o >>= 1) s += __shfl_down(s, o, 64);
    __shared__ int ws[4];
    if ((t & 63) == 0) ws[t >> 6] = s;
    __syncthreads();
    if (t == 0) bsum[blockIdx.x] = ws[0] + ws[1] + ws[2] + ws[3];
}

__global__ __launch_bounds__(256) void scan_k2(int* __restrict__ bsum, int* __restrict__ totalOut, int nb) {
    int t = threadIdx.x;
    int v = (t < nb) ? bsum[t] : 0;
    __shared__ int ts[256];
    ts[t] = v;
    __syncthreads();
    for (int o = 1; o < 256; o <<= 1) {
        int u = (t >= o) ? ts[t - o] : 0;
        __syncthreads();
        ts[t] += u;
        __syncthreads();
    }
    if (t < nb) bsum[t] = ts[t] - v;
    if (t == nb - 1) *totalOut = ts[t];
}

__global__ __launch_bounds__(256) void scan_k3(const int* __restrict__ c, const int* __restrict__ bsum,
                                               const int* __restrict__ total,
                                               int* __restrict__ S, int n) {
    int t = threadIdx.x;
    int base = blockIdx.x * 1024 + t * 4;
    int v[4];
    #pragma unroll
    for (int j = 0; j < 4; j++) v[j] = (base + j < n) ? c[base + j] : 0;
    int tsum = v[0] + v[1] + v[2] + v[3];
    __shared__ int ts[256];
    ts[t] = tsum;
    __syncthreads();
    for (int o = 1; o < 256; o <<= 1) {
        int u = (t >= o) ? ts[t - o] : 0;
        __syncthreads();
        ts[t] += u;
        __syncthreads();
    }
    int run = bsum[blockIdx.x] + ts[t] - tsum;
    #pragma unroll
    for (int j = 0; j < 4; j++) {
        if (base + j < n) { S[base + j] = run; run += v[j]; }
    }
    if (blockIdx.x == 0 && t == 0) S[n] = *total;
}

// A3: bin items into bucket-contiguous (dest,payload) pairs using LDS cursors
__global__ __launch_bounds__(256) void binfill_kernel(
    const int* __restrict__ ei0r, const int* __restrict__ ei0c,
    const int* __restrict__ ei1r, const int* __restrict__ ei1c,
    const int* __restrict__ ei2r, const int* __restrict__ ei2c,
    const int* __restrict__ p1, const int* __restrict__ p2,
    const int* __restrict__ OfsAbs, uint2* __restrict__ binPair)
{
    __shared__ int cur[NBUCK];
    int tid = threadIdx.x, blk = blockIdx.x;
    for (int i = tid; i < NBUCK; i += 256) cur[i] = OfsAbs[i * NBA + blk];
    __syncthreads();
    int base = blk * ITEMS_PER_BLK;
    #pragma unroll
    for (int k = 0; k < 16; k++) {
        int g = base + k * 256 + tid;
        if (g < S4) {
            int c, p;
            item_full(g, ei0r, ei0c, ei1r, ei1c, ei2r, ei2c, p1, p2, c, p);
            int pos = atomicAdd(&cur[c >> 10], 1);
            binPair[pos] = make_uint2((u32)c, (u32)p);
        }
    }
}

// B: per-bucket fine counting sort
__global__ __launch_bounds__(256) void bucket_build_kernel(
    const uint2* __restrict__ binPair, const int* __restrict__ OfsAbs,
    int* __restrict__ rpAll, int* __restrict__ srcU,
    float* __restrict__ dis0, float* __restrict__ dis1, float* __restrict__ dis2)
{
    __shared__ int cnt_l[1024];
    __shared__ int rp_l[1024];
    __shared__ int ts[256];
    int b = blockIdx.x, tid = threadIdx.x;
    int start = OfsAbs[b * NBA];
    int end = (b + 1 < NBUCK) ? OfsAbs[(b + 1) * NBA] : S4;
    int d0 = b << 10;
    int nd = OFFT - d0; if (nd > 1024) nd = 1024;

    for (int i = tid; i < 1024; i += 256) cnt_l[i] = 0;
    __syncthreads();
    for (int i = start + tid; i < end; i += 256) {
        uint2 e = binPair[i];
        atomicAdd(&cnt_l[(int)e.x - d0], 1);
    }
    __syncthreads();
    int bi = tid * 4;
    int v0 = cnt_l[bi], v1 = cnt_l[bi + 1], v2 = cnt_l[bi + 2], v3 = cnt_l[bi + 3];
    int tsum = v0 + v1 + v2 + v3;
    ts[tid] = tsum;
    __syncthreads();
    for (int o = 1; o < 256; o <<= 1) {
        int u = (tid >= o) ? ts[tid - o] : 0;
        __syncthreads();
        ts[tid] += u;
        __syncthreads();
    }
    int run = ts[tid] - tsum;
    rp_l[bi] = run;
    rp_l[bi + 1] = run + v0;
    rp_l[bi + 2] = run + v0 + v1;
    rp_l[bi + 3] = run + v0 + v1 + v2;
    __syncthreads();
    for (int j = tid; j < nd; j += 256) {
        int g = d0 + j;
        rpAll[g] = start + rp_l[j];
        int c = cnt_l[j];
        float dv = rsqrtf((float)(c + 1));
        if (g < OFF1) dis0[g] = dv;
        else if (g < OFF2) dis1[g - OFF1] = dv;
        else if (g < OFF3) dis2[g - OFF2] = dv;
    }
    if (b == NBUCK - 1 && tid == 0) rpAll[OFFT] = S4;
    __syncthreads();
    for (int i = start + tid; i < end; i += 256) {
        uint2 e = binPair[i];
        int pos = start + atomicAdd(&rp_l[(int)e.x - d0], 1);
        srcU[pos] = (int)e.y;
    }
}

__global__ void bn_pre_kernel(const float* __restrict__ g, const float* __restrict__ beta,
                              const float* __restrict__ mean, const float* __restrict__ var,
                              float* __restrict__ scale, float* __restrict__ shift) {
    int i = blockIdx.x * blockDim.x + threadIdx.x;
    if (i < 4 * HDIM) {
        float s = g[i] * rsqrtf(var[i] + EPSBN);
        scale[i] = s;
        shift[i] = beta[i] - mean[i] * s;
    }
}

// ---------------- gather kernels (bf16 features, fp32 accumulate) ----------------
// 8-edge unroll: 8 independent 256B row-loads in flight per wave

#define G128_LOAD(sym, off) u32 sym = y[(long long)srcl[e + off] * 64 + lane]

__global__ __launch_bounds__(256) void gather128_kernel(
    const int* __restrict__ rp, const int* __restrict__ srcl,
    const u32* __restrict__ y, const float* __restrict__ dis,
    const float* __restrict__ bias, u32* __restrict__ h, int n)
{
    int wid = (int)((blockIdx.x * 256 + threadIdx.x) >> 6);
    int lane = threadIdx.x & 63;
    if (wid >= n) return;
    u32 self = y[(long long)wid * 64 + lane];
    float ax = bl(self), ay = bh(self);
    int e = rp[wid], e1 = rp[wid + 1];
    for (; e + 7 < e1; e += 8) {
        G128_LOAD(p0, 0); G128_LOAD(p1, 1); G128_LOAD(p2, 2); G128_LOAD(p3, 3);
        G128_LOAD(p4, 4); G128_LOAD(p5, 5); G128_LOAD(p6, 6); G128_LOAD(p7, 7);
        ax += ((bl(p0) + bl(p1)) + (bl(p2) + bl(p3))) + ((bl(p4) + bl(p5)) + (bl(p6) + bl(p7)));
        ay += ((bh(p0) + bh(p1)) + (bh(p2) + bh(p3))) + ((bh(p4) + bh(p5)) + (bh(p6) + bh(p7)));
    }
    if (e + 3 < e1) {
        G128_LOAD(p0, 0); G128_LOAD(p1, 1); G128_LOAD(p2, 2); G128_LOAD(p3, 3);
        ax += (bl(p0) + bl(p1)) + (bl(p2) + bl(p3));
        ay += (bh(p0) + bh(p1)) + (bh(p2) + bh(p3));
        e += 4;
    }
    if (e + 1 < e1) {
        G128_LOAD(p0, 0); G128_LOAD(p1, 1);
        ax += bl(p0) + bl(p1);
        ay += bh(p0) + bh(p1);
        e += 2;
    }
    if (e < e1) {
        G128_LOAD(p0, 0);
        ax += bl(p0); ay += bh(p0);
    }
    float d = dis[wid];
    float2 b = ((const float2*)bias)[lane];
    float r0 = fmaxf(fmaf(d, ax, b.x), 0.f);
    float r1 = fmaxf(fmaf(d, ay, b.y), 0.f);
    h[(long long)wid * 64 + lane] = pack2(r0, r1);
}

#define GP_LOAD(sym, off) u32 sym = h[(long long)childl[e + off] * 64 + lane]

__global__ __launch_bounds__(256) void gatherP_kernel(
    const int* __restrict__ pp, const int* __restrict__ childl,
    const u32* __restrict__ h, u32* __restrict__ p, int n)
{
    int wid = (int)((blockIdx.x * 256 + threadIdx.x) >> 6);
    int lane = threadIdx.x & 63;
    if (wid >= n) return;
    float ax = 0.f, ay = 0.f;
    int e = pp[wid], e1 = pp[wid + 1];
    for (; e + 7 < e1; e += 8) {
        GP_LOAD(p0, 0); GP_LOAD(p1, 1); GP_LOAD(p2, 2); GP_LOAD(p3, 3);
        GP_LOAD(p4, 4); GP_LOAD(p5, 5); GP_LOAD(p6, 6); GP_LOAD(p7, 7);
        ax += ((bl(p0) + bl(p1)) + (bl(p2) + bl(p3))) + ((bl(p4) + bl(p5)) + (bl(p6) + bl(p7)));
        ay += ((bh(p0) + bh(p1)) + (bh(p2) + bh(p3))) + ((bh(p4) + bh(p5)) + (bh(p6) + bh(p7)));
    }
    if (e + 3 < e1) {
        GP_LOAD(p0, 0); GP_LOAD(p1, 1); GP_LOAD(p2, 2); GP_LOAD(p3, 3);
        ax += (bl(p0) + bl(p1)) + (bl(p2) + bl(p3));
        ay += (bh(p0) + bh(p1)) + (bh(p2) + bh(p3));
        e += 4;
    }
    if (e + 1 < e1) {
        GP_LOAD(p0, 0); GP_LOAD(p1, 1);
        ax += bl(p0) + bl(p1);
        ay += bh(p0) + bh(p1);
        e += 2;
    }
    if (e < e1) {
        GP_LOAD(p0, 0);
        ax += bl(p0); ay += bh(p0);
    }
    p[(long long)wid * 64 + lane] = pack2(ax, ay);
}

// Final: gather bf16 32B rows + bias + log_softmax; 4-edge unroll
__global__ __launch_bounds__(256) void gather10_lsm_kernel(
    const int* __restrict__ rp, const int* __restrict__ srcl,
    const u32* __restrict__ y4, const float* __restrict__ dis,
    const float* __restrict__ bias, float* __restrict__ out, int n)
{
    int c = blockIdx.x * blockDim.x + threadIdx.x;
    if (c >= n) return;
    float acc[10];
    {
        long long base = (long long)c * 8;
        uint4 q = *(const uint4*)(y4 + base);
        u32 q4 = y4[base + 4];
        acc[0] = bl(q.x); acc[1] = bh(q.x);
        acc[2] = bl(q.y); acc[3] = bh(q.y);
        acc[4] = bl(q.z); acc[5] = bh(q.z);
        acc[6] = bl(q.w); acc[7] = bh(q.w);
        acc[8] = bl(q4);  acc[9] = bh(q4);
    }
    int e = rp[c], e1 = rp[c + 1];
    for (; e + 3 < e1; e += 4) {
        long long bA = (long long)srcl[e] * 8;
        long long bB = (long long)srcl[e + 1] * 8;
        long long bC = (long long)srcl[e + 2] * 8;
        long long bD = (long long)srcl[e + 3] * 8;
        uint4 qa = *(const uint4*)(y4 + bA); u32 qa4 = y4[bA + 4];
        uint4 qb = *(const uint4*)(y4 + bB); u32 qb4 = y4[bB + 4];
        uint4 qc = *(const uint4*)(y4 + bC); u32 qc4 = y4[bC + 4];
        uint4 qd = *(const uint4*)(y4 + bD); u32 qd4 = y4[bD + 4];
        acc[0] += (bl(qa.x) + bl(qb.x)) + (bl(qc.x) + bl(qd.x));
        acc[1] += (bh(qa.x) + bh(qb.x)) + (bh(qc.x) + bh(qd.x));
        acc[2] += (bl(qa.y) + bl(qb.y)) + (bl(qc.y) + bl(qd.y));
        acc[3] += (bh(qa.y) + bh(qb.y)) + (bh(qc.y) + bh(qd.y));
        acc[4] += (bl(qa.z) + bl(qb.z)) + (bl(qc.z) + bl(qd.z));
        acc[5] += (bh(qa.z) + bh(qb.z)) + (bh(qc.z) + bh(qd.z));
        acc[6] += (bl(qa.w) + bl(qb.w)) + (bl(qc.w) + bl(qd.w));
        acc[7] += (bh(qa.w) + bh(qb.w)) + (bh(qc.w) + bh(qd.w));
        acc[8] += (bl(qa4) + bl(qb4)) + (bl(qc4) + bl(qd4));
        acc[9] += (bh(qa4) + bh(qb4)) + (bh(qc4) + bh(qd4));
    }
    for (; e < e1; e++) {
        long long bA = (long long)srcl[e] * 8;
        uint4 qa = *(const uint4*)(y4 + bA);
        u32 qa4 = y4[bA + 4];
        acc[0] += bl(qa.x); acc[1] += bh(qa.x);
        acc[2] += bl(qa.y); acc[3] += bh(qa.y);
        acc[4] += bl(qa.z); acc[5] += bh(qa.z);
        acc[6] += bl(qa.w); acc[7] += bh(qa.w);
        acc[8] += bl(qa4);  acc[9] += bh(qa4);
    }
    float d = dis[c];
    float m = -1e30f;
    #pragma unroll
    for (int k = 0; k < 10; k++) {
        acc[k] = fmaf(d, acc[k], bias[k]);
        m = fmaxf(m, acc[k]);
    }
    float s = 0.f;
    #pragma unroll
    for (int k = 0; k < 10; k++) s += expf(acc[k] - m);
    float ls = logf(s);
    #pragma unroll
    for (int k = 0; k < 10; k++) out[(long long)c * 10 + k] = acc[k] - m - ls;
}

// ---------------- MFMA matmul K=128, N=128 ----------------
__global__ __launch_bounds__(256) void mm128_kernel(
    const void* __restrict__ Av, const float* __restrict__ W,
    u32* __restrict__ out, int M,
    const float* __restrict__ dis,
    const u32* __restrict__ gsrc, const int* __restrict__ gidx,
    const float* __restrict__ bias,
    const float* __restrict__ bnscale, const float* __restrict__ bnshift,
    int pool, int afp32)
{
    __shared__ u32 WL[8192];   // [t=8][s=4][lane=64][i=4]
    int tid = threadIdx.x;

    #pragma unroll
    for (int it = 0; it < 32; it++) {
        int flat = it * 256 + tid;
        int i = flat & 3;
        int ln = (flat >> 2) & 63;
        int s = (flat >> 8) & 3;
        int t = flat >> 10;
        int mm = ln & 15, qq = ln >> 4;
        int k0 = s * 32 + qq * 8 + 2 * i;
        int col = t * 16 + mm;
        WL[flat] = pack2(W[k0 * 128 + col], W[(k0 + 1) * 128 + col]);
    }
    __syncthreads();

    int lane = tid & 63;
    int w = tid >> 6;
    int m = lane & 15, q = lane >> 4;
    int row = blockIdx.x * 64 + w * 16 + m;
    bool live = (row < M);

    uint4 xb[4];
    if (live) {
        if (afp32) {
            const float* Af = (const float*)Av;
            #pragma unroll
            for (int s = 0; s < 4; s++) {
                const float4* p = (const float4*)(Af + (long long)row * 128 + s * 32 + q * 8);
                float4 f0 = p[0], f1 = p[1];
                xb[s].x = pack2(f0.x, f0.y);
                xb[s].y = pack2(f0.z, f0.w);
                xb[s].z = pack2(f1.x, f1.y);
                xb[s].w = pack2(f1.z, f1.w);
            }
        } else {
            const u32* Ab = (const u32*)Av;
            #pragma unroll
            for (int s = 0; s < 4; s++)
                xb[s] = *(const uint4*)(Ab + (long long)row * 64 + s * 16 + q * 4);
        }
    } else {
        xb[0] = xb[1] = xb[2] = xb[3] = make_uint4(0u, 0u, 0u, 0u);
    }

    float d = 1.0f;
    if (dis && live) d = dis[row];
    long long gbase = (gsrc && live) ? (long long)gidx[row] * 64 : 0;

    #pragma unroll
    for (int t = 0; t < 8; t++) {
        f32x4 acc = {0.f, 0.f, 0.f, 0.f};
        #pragma unroll
        for (int s = 0; s < 4; s++) {
            uint4 wa = *(const uint4*)&WL[((t * 4 + s) * 64 + lane) * 4];
            acc = __builtin_amdgcn_mfma_f32_16x16x32_bf16(asbf(wa), asbf(xb[s]), acc, 0, 0, 0);
        }
        if (live) {
            float v0 = acc[0], v1 = acc[1], v2 = acc[2], v3 = acc[3];
            int cbase = t * 16 + q * 4;
            if (gsrc) {
                uint2 g = *(const uint2*)(gsrc + gbase + (cbase >> 1));
                v0 += bl(g.x); v1 += bh(g.x);
                v2 += bl(g.y); v3 += bh(g.y);
            }
            if (pool) {
                float4 bb = *(const float4*)(bias + cbase);
                float4 sc = *(const float4*)(bnscale + cbase);
                float4 sh = *(const float4*)(bnshift + cbase);
                v0 = fmaxf(fmaxf(v0 + bb.x, 0.f) * sc.x + sh.x, 0.f);
                v1 = fmaxf(fmaxf(v1 + bb.y, 0.f) * sc.y + sh.y, 0.f);
                v2 = fmaxf(fmaxf(v2 + bb.z, 0.f) * sc.z + sh.z, 0.f);
                v3 = fmaxf(fmaxf(v3 + bb.w, 0.f) * sc.w + sh.w, 0.f);
            }
            v0 *= d; v1 *= d; v2 *= d; v3 *= d;
            uint2 st;
            st.x = pack2(v0, v1);
            st.y = pack2(v2, v3);
            *(uint2*)(out + (long long)row * 64 + (cbase >> 1)) = st;
        }
    }
}

// ---------------- matmul K=128, N=10; bf16 A, fp32 W, fp32 out ----------------
__global__ __launch_bounds__(256) void mm10_kernel(
    const u32* __restrict__ A, const float* __restrict__ W,
    float* __restrict__ out, int M)
{
    __shared__ float Ws[128 * 10];
    for (int i = threadIdx.x; i < 1280; i += 256) Ws[i] = W[i];
    __syncthreads();
    int row = blockIdx.x * blockDim.x + threadIdx.x;
    if (row >= M) return;
    const uint4* a = (const uint4*)(A + (long long)row * 64);
    float acc[10] = {0, 0, 0, 0, 0, 0, 0, 0, 0, 0};
    #pragma unroll 4
    for (int i = 0; i < 16; i++) {
        uint4 av = a[i];
        int k = i * 8;
        float f[8] = { bl(av.x), bh(av.x), bl(av.y), bh(av.y),
                       bl(av.z), bh(av.z), bl(av.w), bh(av.w) };
        #pragma unroll
        for (int j = 0; j < 8; j++) {
            #pragma unroll
            for (int cc = 0; cc < 10; cc++)
                acc[cc] += f[j] * Ws[(k + j) * 10 + cc];
        }
    }
    #pragma unroll
    for (int cc = 0; cc < 10; cc++) out[(long long)row * 10 + cc] = acc[cc];
}

__global__ __launch_bounds__(256) void mm10p_kernel(
    const u32* __restrict__ A, const float* __restrict__ W,
    u32* __restrict__ outp, int M,
    const float* __restrict__ dis,
    const float* __restrict__ gsrc, const int* __restrict__ gidx)
{
    __shared__ float Ws[128 * 10];
    for (int i = threadIdx.x; i < 1280; i += 256) Ws[i] = W[i];
    __syncthreads();
    int row = blockIdx.x * blockDim.x + threadIdx.x;
    if (row >= M) return;
    const uint4* a = (const uint4*)(A + (long long)row * 64);
    float acc[10] = {0, 0, 0, 0, 0, 0, 0, 0, 0, 0};
    #pragma unroll 4
    for (int i = 0; i < 16; i++) {
        uint4 av = a[i];
        int k = i * 8;
        float f[8] = { bl(av.x), bh(av.x), bl(av.y), bh(av.y),
                       bl(av.z), bh(av.z), bl(av.w), bh(av.w) };
        #pragma unroll
        for (int j = 0; j < 8; j++) {
            #pragma unroll
            for (int cc = 0; cc < 10; cc++)
                acc[cc] += f[j] * Ws[(k + j) * 10 + cc];
        }
    }
    float d = dis[row];
    const float* g = gsrc + (long long)gidx[row] * 10;
    long long base = (long long)row * 8;
    #pragma unroll
    for (int j = 0; j < 5; j++) {
        float v0 = (acc[2 * j] + g[2 * j]) * d;
        float v1 = (acc[2 * j + 1] + g[2 * j + 1]) * d;
        outp[base + j] = pack2(v0, v1);
    }
}

// ---------------- launcher ----------------

extern "C" void kernel_launch(void* const* d_in, const int* in_sizes, int n_in,
                              void* d_out, int out_size, void* d_ws, size_t ws_size,
                              hipStream_t stream) {
    const float* x       = (const float*)d_in[0];
    const int*   ei0     = (const int*)d_in[1];
    const int*   ei1     = (const int*)d_in[2];
    const int*   ei2     = (const int*)d_in[3];
    const int*   parent1 = (const int*)d_in[4];
    const int*   parent2 = (const int*)d_in[5];
    const float* W0 = (const float*)d_in[6];
    const float* b0 = (const float*)d_in[7];
    const float* W1 = (const float*)d_in[8];
    const float* b1 = (const float*)d_in[9];
    const float* W2 = (const float*)d_in[10];
    const float* b2 = (const float*)d_in[11];
    const float* W3 = (const float*)d_in[12];
    const float* b3 = (const float*)d_in[13];
    const float* W4 = (const float*)d_in[14];
    const float* b4 = (const float*)d_in[15];
    const float* pW = (const float*)d_in[16];
    const float* pb = (const float*)d_in[17];
    const float* pg = (const float*)d_in[18];
    const float* pbeta = (const float*)d_in[19];
    const float* pmean = (const float*)d_in[20];
    const float* pvar  = (const float*)d_in[21];
    float* out = (float*)d_out;

    char* ws = (char*)d_ws;
    size_t off = 0;
    auto alloc = [&](size_t nbytes) -> char* {
        char* p = ws + off;
        off += ((nbytes + 255) / 256) * 256;
        return p;
    };
    float* dis0 = (float*)alloc(N0 * 4);
    float* dis1 = (float*)alloc(N1 * 4);
    float* dis2 = (float*)alloc(N2 * 4);
    float* bnscale = (float*)alloc(4 * HDIM * 4);
    float* bnshift = (float*)alloc(4 * HDIM * 4);
    float* W1b = (float*)alloc((size_t)N1 * 10 * 4);
    u32* Y   = (u32*)alloc((size_t)N0 * 64 * 4);
    u32* H0  = (u32*)alloc((size_t)N0 * 64 * 4);
    u32* H1  = (u32*)alloc((size_t)N1 * 64 * 4);
    u32* P   = (u32*)alloc((size_t)N1 * 64 * 4);
    u32* X1  = (u32*)alloc((size_t)N1 * 64 * 4);
    u32* HU1 = (u32*)alloc((size_t)N1 * 64 * 4);
    u32* U1  = (u32*)alloc((size_t)N1 * 64 * 4);
    u32* X2  = (u32*)alloc((size_t)N2 * 64 * 4);
    u32* H2  = (u32*)alloc((size_t)N2 * 64 * 4);
    u32* U2  = (u32*)alloc((size_t)N2 * 64 * 4);
    u32* V2  = (u32*)alloc((size_t)N2 * 64 * 4);
    u32* Y4p = (u32*)alloc((size_t)N0 * 8 * 4);
    int* rpAll = (int*)alloc((size_t)(OFFT + 1) * 4);
    int* srcU  = (int*)alloc((size_t)S4 * 4);
    int*   blockHist = (int*)alloc((size_t)BH_N * 4);
    int*   OfsAbs    = (int*)alloc((size_t)(BH_N + 1) * 4);
    uint2* binPair   = (uint2*)alloc((size_t)S4 * 8);
    int* bsum   = (int*)alloc(NBLK2 * 4);
    int* totalb = (int*)alloc(4);

    const int B = 256;
    auto G = [](long long t) { return (unsigned)((t + 255) / 256); };
    auto G64 = [](long long m) { return (unsigned)((m + 63) / 64); };

    // ---- CSR build (LDS counting sort, no global atomics) ----
    binhist_kernel<<<NBA, B, 0, stream>>>(
        ei0 + E0C, ei1 + E1C, ei2 + E2C, parent1, parent2, blockHist);
    scan_k1<<<NBLK2, B, 0, stream>>>(blockHist, bsum, BH_N);
    scan_k2<<<1, B, 0, stream>>>(bsum, totalb, NBLK2);
    scan_k3<<<NBLK2, B, 0, stream>>>(blockHist, bsum, totalb, OfsAbs, BH_N);
    binfill_kernel<<<NBA, B, 0, stream>>>(
        ei0, ei0 + E0C, ei1, ei1 + E1C, ei2, ei2 + E2C, parent1, parent2, OfsAbs, binPair);
    bucket_build_kernel<<<NBUCK, B, 0, stream>>>(
        binPair, OfsAbs, rpAll, srcU, dis0, dis1, dis2);
    bn_pre_kernel<<<2, B, 0, stream>>>(pg, pbeta, pmean, pvar, bnscale, bnshift);

    // ---- gcn0 ----
    mm128_kernel<<<G64(N0), B, 0, stream>>>(
        x, W0, Y, N0, dis0, nullptr, nullptr, nullptr, nullptr, nullptr, 0, 1);
    gather128_kernel<<<G((long long)N0 * 64), B, 0, stream>>>(rpAll + OFF0, srcU, Y, dis0, b0, H0, N0);

    // ---- pool1 ----
    gatherP_kernel<<<G((long long)N1 * 64), B, 0, stream>>>(rpAll + OFF3, srcU, H0, P, N1);
    mm128_kernel<<<G64(N1), B, 0, stream>>>(
        P, pW, X1, N1, nullptr, nullptr, nullptr, pb, bnscale, bnshift, 1, 0);

    // ---- gcn1 ----
    mm128_kernel<<<G64(N1), B, 0, stream>>>(
        X1, W1, Y, N1, dis1, nullptr, nullptr, nullptr, nullptr, nullptr, 0, 0);
    gather128_kernel<<<G((long long)N1 * 64), B, 0, stream>>>(rpAll + OFF1, srcU, Y, dis1, b1, H1, N1);

    // ---- pool2 ----
    gatherP_kernel<<<G((long long)N2 * 64), B, 0, stream>>>(rpAll + OFF4, srcU, H1, P, N2);
    mm128_kernel<<<G64(N2), B, 0, stream>>>(
        P, pW + 128 * 128, X2, N2, nullptr, nullptr, nullptr, pb + 128, bnscale + 128, bnshift + 128, 1, 0);

    // ---- gcn2 ----
    mm128_kernel<<<G64(N2), B, 0, stream>>>(
        X2, W2, Y, N2, dis2, nullptr, nullptr, nullptr, nullptr, nullptr, 0, 0);
    gather128_kernel<<<G((long long)N2 * 64), B, 0, stream>>>(rpAll + OFF2, srcU, Y, dis2, b2, H2, N2);

    // ---- up level 2 ----
    mm128_kernel<<<G64(N2), B, 0, stream>>>(
        H2, pW + 2 * 128 * 128, U2, N2, nullptr, nullptr, nullptr, pb + 256, bnscale + 256, bnshift + 256, 1, 0);
    mm128_kernel<<<G64(N2), B, 0, stream>>>(
        U2, W3, V2, N2, nullptr, nullptr, nullptr, nullptr, nullptr, nullptr, 0, 0);

    // ---- gcn3 ----
    mm128_kernel<<<G64(N1), B, 0, stream>>>(
        H1, W3 + 128 * 128, Y, N1, dis1, V2, parent2, nullptr, nullptr, nullptr, 0, 0);
    gather128_kernel<<<G((long long)N1 * 64), B, 0, stream>>>(rpAll + OFF1, srcU, Y, dis1, b3, HU1, N1);

    // ---- up level 1 ----
    mm128_kernel<<<G64(N1), B, 0, stream>>>(
        HU1, pW + 3 * 128 * 128, U1, N1, nullptr, nullptr, nullptr, pb + 384, bnscale + 384, bnshift + 384, 1, 0);
    mm10_kernel<<<G(N1), B, 0, stream>>>(U1, W4, W1b, N1);

    // ---- gcn4 ----
    mm10p_kernel<<<G(N0), B, 0, stream>>>(H0, W4 + 128 * 10, Y4p, N0, dis0, W1b, parent1);
    gather10_lsm_kernel<<<G(N0), B, 0, stream>>>(rpAll + OFF0, srcU, Y4p, dis0, b4, out, N0);
}

// Round 14
// 447.388 us; speedup vs baseline: 1.1840x; 1.0042x over previous
//
#include <hip/hip_runtime.h>
#include <math.h>

#define N0 100000
#define N1 20000
#define N2 4000
#define HDIM 128
#define E0C 1600000
#define E1C 320000
#define E2C 64000
#define EPSBN 1e-5f

typedef unsigned int u32;
typedef float f32x4 __attribute__((ext_vector_type(4)));
typedef short bf16x8 __attribute__((ext_vector_type(8)));

union FragU { uint4 u; bf16x8 h; };
__device__ __forceinline__ bf16x8 asbf(uint4 v) { FragU x; x.u = v; return x.h; }

__device__ __forceinline__ float bl(u32 p) { return __uint_as_float(p << 16); }
__device__ __forceinline__ float bh(u32 p) { return __uint_as_float(p & 0xFFFF0000u); }
__device__ __forceinline__ u32 pack2(float a, float b) {
    u32 ua = __float_as_uint(a), ub = __float_as_uint(b);
    ua = (ua + 0x7FFFu + ((ua >> 16) & 1u)) >> 16;
    ub = (ub + 0x7FFFu + ((ub >> 16) & 1u)) >> 16;
    return ua | (ub << 16);
}

// concatenated destination space
#define OFF0 0
#define OFF1 (N0)
#define OFF2 (N0 + N1)
#define OFF3 (N0 + N1 + N2)
#define OFF4 (N0 + N1 + N2 + N1)
#define OFFT (N0 + N1 + N2 + N1 + N2)        // 148000

// concatenated work items
#define S0 (E0C)
#define S1 (E0C + E1C)
#define S2 (E0C + E1C + E2C)
#define S3 (E0C + E1C + E2C + N0)
#define S4 (E0C + E1C + E2C + N0 + N1)       // 2,104,000

// counting-sort geometry
#define NBUCK ((OFFT + 1023) / 1024)         // 145 coarse buckets
#define ITEMS_PER_BLK 4096
#define NBA ((S4 + ITEMS_PER_BLK - 1) / ITEMS_PER_BLK)   // 514 blocks
#define BH_N (NBUCK * NBA)
#define NBLK2 ((BH_N + 1023) / 1024)

// ---------------- CSR build (LDS counting sort, zero global atomics) ----------------
// binPair entry: (concat&1023)<<17 | payload   (payload < 2^17, bucket implied by position)

__device__ __forceinline__ void item_full(int g,
    const int* __restrict__ ei0r, const int* __restrict__ ei0c,
    const int* __restrict__ ei1r, const int* __restrict__ ei1c,
    const int* __restrict__ ei2r, const int* __restrict__ ei2c,
    const int* __restrict__ p1, const int* __restrict__ p2,
    int& concat, int& payload)
{
    if (g < S0)      { concat = ei0c[g];             payload = ei0r[g]; }
    else if (g < S1) { int i = g - S0; concat = OFF1 + ei1c[i]; payload = ei1r[i]; }
    else if (g < S2) { int i = g - S1; concat = OFF2 + ei2c[i]; payload = ei2r[i]; }
    else if (g < S3) { int i = g - S2; concat = OFF3 + p1[i];   payload = i; }
    else             { int i = g - S3; concat = OFF4 + p2[i];   payload = i; }
}

__device__ __forceinline__ int item_concat(int g,
    const int* __restrict__ ei0c, const int* __restrict__ ei1c, const int* __restrict__ ei2c,
    const int* __restrict__ p1, const int* __restrict__ p2)
{
    if (g < S0)      return ei0c[g];
    else if (g < S1) return OFF1 + ei1c[g - S0];
    else if (g < S2) return OFF2 + ei2c[g - S1];
    else if (g < S3) return OFF3 + p1[g - S2];
    else             return OFF4 + p2[g - S3];
}

__global__ __launch_bounds__(256) void binhist_kernel(
    const int* __restrict__ ei0c, const int* __restrict__ ei1c, const int* __restrict__ ei2c,
    const int* __restrict__ p1, const int* __restrict__ p2,
    int* __restrict__ blockHist)
{
    __shared__ int hist[NBUCK];
    int tid = threadIdx.x, blk = blockIdx.x;
    for (int i = tid; i < NBUCK; i += 256) hist[i] = 0;
    __syncthreads();
    int base = blk * ITEMS_PER_BLK;
    #pragma unroll
    for (int k = 0; k < 16; k++) {
        int g = base + k * 256 + tid;
        if (g < S4) {
            int c = item_concat(g, ei0c, ei1c, ei2c, p1, p2);
            atomicAdd(&hist[c >> 10], 1);
        }
    }
    __syncthreads();
    for (int b = tid; b < NBUCK; b += 256) blockHist[b * NBA + blk] = hist[b];
}

__global__ __launch_bounds__(256) void scan_k1(const int* __restrict__ c, int* __restrict__ bsum, int n) {
    int t = threadIdx.x;
    int base = blockIdx.x * 1024 + t * 4;
    int s = 0;
    #pragma unroll
    for (int j = 0; j < 4; j++) {
        int idx = base + j;
        if (idx < n) s += c[idx];
    }
    #pragma unroll
    for (int o = 32; o > 0; o >>= 1) s += __shfl_down(s, o, 64);
    __shared__ int ws[4];
    if ((t & 63) == 0) ws[t >> 6] = s;
    __syncthreads();
    if (t == 0) bsum[blockIdx.x] = ws[0] + ws[1] + ws[2] + ws[3];
}

__global__ __launch_bounds__(256) void scan_k2(int* __restrict__ bsum, int* __restrict__ totalOut, int nb) {
    int t = threadIdx.x;
    int v = (t < nb) ? bsum[t] : 0;
    __shared__ int ts[256];
    ts[t] = v;
    __syncthreads();
    for (int o = 1; o < 256; o <<= 1) {
        int u = (t >= o) ? ts[t - o] : 0;
        __syncthreads();
        ts[t] += u;
        __syncthreads();
    }
    if (t < nb) bsum[t] = ts[t] - v;
    if (t == nb - 1) *totalOut = ts[t];
}

__global__ __launch_bounds__(256) void scan_k3(const int* __restrict__ c, const int* __restrict__ bsum,
                                               const int* __restrict__ total,
                                               int* __restrict__ S, int n) {
    int t = threadIdx.x;
    int base = blockIdx.x * 1024 + t * 4;
    int v[4];
    #pragma unroll
    for (int j = 0; j < 4; j++) v[j] = (base + j < n) ? c[base + j] : 0;
    int tsum = v[0] + v[1] + v[2] + v[3];
    __shared__ int ts[256];
    ts[t] = tsum;
    __syncthreads();
    for (int o = 1; o < 256; o <<= 1) {
        int u = (t >= o) ? ts[t - o] : 0;
        __syncthreads();
        ts[t] += u;
        __syncthreads();
    }
    int run = bsum[blockIdx.x] + ts[t] - tsum;
    #pragma unroll
    for (int j = 0; j < 4; j++) {
        if (base + j < n) { S[base + j] = run; run += v[j]; }
    }
    if (blockIdx.x == 0 && t == 0) S[n] = *total;
}

__global__ __launch_bounds__(256) void binfill_kernel(
    const int* __restrict__ ei0r, const int* __restrict__ ei0c,
    const int* __restrict__ ei1r, const int* __restrict__ ei1c,
    const int* __restrict__ ei2r, const int* __restrict__ ei2c,
    const int* __restrict__ p1, const int* __restrict__ p2,
    const int* __restrict__ OfsAbs, u32* __restrict__ binPair)
{
    __shared__ int cur[NBUCK];
    int tid = threadIdx.x, blk = blockIdx.x;
    for (int i = tid; i < NBUCK; i += 256) cur[i] = OfsAbs[i * NBA + blk];
    __syncthreads();
    int base = blk * ITEMS_PER_BLK;
    #pragma unroll
    for (int k = 0; k < 16; k++) {
        int g = base + k * 256 + tid;
        if (g < S4) {
            int c, p;
            item_full(g, ei0r, ei0c, ei1r, ei1c, ei2r, ei2c, p1, p2, c, p);
            int pos = atomicAdd(&cur[c >> 10], 1);
            binPair[pos] = ((u32)(c & 1023) << 17) | (u32)p;
        }
    }
}

__global__ __launch_bounds__(256) void bucket_build_kernel(
    const u32* __restrict__ binPair, const int* __restrict__ OfsAbs,
    int* __restrict__ rpAll, int* __restrict__ srcU,
    float* __restrict__ dis0, float* __restrict__ dis1, float* __restrict__ dis2)
{
    __shared__ int cnt_l[1024];
    __shared__ int rp_l[1024];
    __shared__ int ts[256];
    int b = blockIdx.x, tid = threadIdx.x;
    int start = OfsAbs[b * NBA];
    int end = (b + 1 < NBUCK) ? OfsAbs[(b + 1) * NBA] : S4;
    int d0 = b << 10;
    int nd = OFFT - d0; if (nd > 1024) nd = 1024;

    for (int i = tid; i < 1024; i += 256) cnt_l[i] = 0;
    __syncthreads();
    for (int i = start + tid; i < end; i += 256) {
        u32 e = binPair[i];
        atomicAdd(&cnt_l[e >> 17], 1);
    }
    __syncthreads();
    int bi = tid * 4;
    int v0 = cnt_l[bi], v1 = cnt_l[bi + 1], v2 = cnt_l[bi + 2], v3 = cnt_l[bi + 3];
    int tsum = v0 + v1 + v2 + v3;
    ts[tid] = tsum;
    __syncthreads();
    for (int o = 1; o < 256; o <<= 1) {
        int u = (tid >= o) ? ts[tid - o] : 0;
        __syncthreads();
        ts[tid] += u;
        __syncthreads();
    }
    int run = ts[tid] - tsum;
    rp_l[bi] = run;
    rp_l[bi + 1] = run + v0;
    rp_l[bi + 2] = run + v0 + v1;
    rp_l[bi + 3] = run + v0 + v1 + v2;
    __syncthreads();
    for (int j = tid; j < nd; j += 256) {
        int g = d0 + j;
        rpAll[g] = start + rp_l[j];
        int c = cnt_l[j];
        float dv = rsqrtf((float)(c + 1));
        if (g < OFF1) dis0[g] = dv;
        else if (g < OFF2) dis1[g - OFF1] = dv;
        else if (g < OFF3) dis2[g - OFF2] = dv;
    }
    if (b == NBUCK - 1 && tid == 0) rpAll[OFFT] = S4;
    __syncthreads();
    for (int i = start + tid; i < end; i += 256) {
        u32 e = binPair[i];
        int pos = start + atomicAdd(&rp_l[e >> 17], 1);
        srcU[pos] = (int)(e & 0x1FFFFu);
    }
}

__global__ void bn_pre_kernel(const float* __restrict__ g, const float* __restrict__ beta,
                              const float* __restrict__ mean, const float* __restrict__ var,
                              float* __restrict__ scale, float* __restrict__ shift) {
    int i = blockIdx.x * blockDim.x + threadIdx.x;
    if (i < 4 * HDIM) {
        float s = g[i] * rsqrtf(var[i] + EPSBN);
        scale[i] = s;
        shift[i] = beta[i] - mean[i] * s;
    }
}

// ---------------- gather kernels (bf16 features, fp32 accumulate) ----------------
// 16-edge unroll: 16 independent 256B row-loads in flight per wave

#define G128_LOAD(sym, off) u32 sym = y[(long long)srcl[e + off] * 64 + lane]

__global__ __launch_bounds__(256) void gather128_kernel(
    const int* __restrict__ rp, const int* __restrict__ srcl,
    const u32* __restrict__ y, const float* __restrict__ dis,
    const float* __restrict__ bias, u32* __restrict__ h, int n)
{
    int wid = (int)((blockIdx.x * 256 + threadIdx.x) >> 6);
    int lane = threadIdx.x & 63;
    if (wid >= n) return;
    u32 self = y[(long long)wid * 64 + lane];
    float ax = bl(self), ay = bh(self);
    int e = rp[wid], e1 = rp[wid + 1];
    for (; e + 15 < e1; e += 16) {
        G128_LOAD(p0, 0); G128_LOAD(p1, 1); G128_LOAD(p2, 2); G128_LOAD(p3, 3);
        G128_LOAD(p4, 4); G128_LOAD(p5, 5); G128_LOAD(p6, 6); G128_LOAD(p7, 7);
        G128_LOAD(p8, 8); G128_LOAD(p9, 9); G128_LOAD(pa, 10); G128_LOAD(pb, 11);
        G128_LOAD(pc, 12); G128_LOAD(pd, 13); G128_LOAD(pe, 14); G128_LOAD(pf, 15);
        ax += (((bl(p0) + bl(p1)) + (bl(p2) + bl(p3))) + ((bl(p4) + bl(p5)) + (bl(p6) + bl(p7))))
            + (((bl(p8) + bl(p9)) + (bl(pa) + bl(pb))) + ((bl(pc) + bl(pd)) + (bl(pe) + bl(pf))));
        ay += (((bh(p0) + bh(p1)) + (bh(p2) + bh(p3))) + ((bh(p4) + bh(p5)) + (bh(p6) + bh(p7))))
            + (((bh(p8) + bh(p9)) + (bh(pa) + bh(pb))) + ((bh(pc) + bh(pd)) + (bh(pe) + bh(pf))));
    }
    if (e + 7 < e1) {
        G128_LOAD(p0, 0); G128_LOAD(p1, 1); G128_LOAD(p2, 2); G128_LOAD(p3, 3);
        G128_LOAD(p4, 4); G128_LOAD(p5, 5); G128_LOAD(p6, 6); G128_LOAD(p7, 7);
        ax += ((bl(p0) + bl(p1)) + (bl(p2) + bl(p3))) + ((bl(p4) + bl(p5)) + (bl(p6) + bl(p7)));
        ay += ((bh(p0) + bh(p1)) + (bh(p2) + bh(p3))) + ((bh(p4) + bh(p5)) + (bh(p6) + bh(p7)));
        e += 8;
    }
    if (e + 3 < e1) {
        G128_LOAD(p0, 0); G128_LOAD(p1, 1); G128_LOAD(p2, 2); G128_LOAD(p3, 3);
        ax += (bl(p0) + bl(p1)) + (bl(p2) + bl(p3));
        ay += (bh(p0) + bh(p1)) + (bh(p2) + bh(p3));
        e += 4;
    }
    if (e + 1 < e1) {
        G128_LOAD(p0, 0); G128_LOAD(p1, 1);
        ax += bl(p0) + bl(p1);
        ay += bh(p0) + bh(p1);
        e += 2;
    }
    if (e < e1) {
        G128_LOAD(p0, 0);
        ax += bl(p0); ay += bh(p0);
    }
    float d = dis[wid];
    float2 b = ((const float2*)bias)[lane];
    float r0 = fmaxf(fmaf(d, ax, b.x), 0.f);
    float r1 = fmaxf(fmaf(d, ay, b.y), 0.f);
    h[(long long)wid * 64 + lane] = pack2(r0, r1);
}

#define GP_LOAD(sym, off) u32 sym = h[(long long)childl[e + off] * 64 + lane]

__global__ __launch_bounds__(256) void gatherP_kernel(
    const int* __restrict__ pp, const int* __restrict__ childl,
    const u32* __restrict__ h, u32* __restrict__ p, int n)
{
    int wid = (int)((blockIdx.x * 256 + threadIdx.x) >> 6);
    int lane = threadIdx.x & 63;
    if (wid >= n) return;
    float ax = 0.f, ay = 0.f;
    int e = pp[wid], e1 = pp[wid + 1];
    for (; e + 7 < e1; e += 8) {
        GP_LOAD(p0, 0); GP_LOAD(p1, 1); GP_LOAD(p2, 2); GP_LOAD(p3, 3);
        GP_LOAD(p4, 4); GP_LOAD(p5, 5); GP_LOAD(p6, 6); GP_LOAD(p7, 7);
        ax += ((bl(p0) + bl(p1)) + (bl(p2) + bl(p3))) + ((bl(p4) + bl(p5)) + (bl(p6) + bl(p7)));
        ay += ((bh(p0) + bh(p1)) + (bh(p2) + bh(p3))) + ((bh(p4) + bh(p5)) + (bh(p6) + bh(p7)));
    }
    if (e + 3 < e1) {
        GP_LOAD(p0, 0); GP_LOAD(p1, 1); GP_LOAD(p2, 2); GP_LOAD(p3, 3);
        ax += (bl(p0) + bl(p1)) + (bl(p2) + bl(p3));
        ay += (bh(p0) + bh(p1)) + (bh(p2) + bh(p3));
        e += 4;
    }
    if (e + 1 < e1) {
        GP_LOAD(p0, 0); GP_LOAD(p1, 1);
        ax += bl(p0) + bl(p1);
        ay += bh(p0) + bh(p1);
        e += 2;
    }
    if (e < e1) {
        GP_LOAD(p0, 0);
        ax += bl(p0); ay += bh(p0);
    }
    p[(long long)wid * 64 + lane] = pack2(ax, ay);
}

__global__ __launch_bounds__(256) void gather10_lsm_kernel(
    const int* __restrict__ rp, const int* __restrict__ srcl,
    const u32* __restrict__ y4, const float* __restrict__ dis,
    const float* __restrict__ bias, float* __restrict__ out, int n)
{
    int c = blockIdx.x * blockDim.x + threadIdx.x;
    if (c >= n) return;
    float acc[10];
    {
        long long base = (long long)c * 8;
        uint4 q = *(const uint4*)(y4 + base);
        u32 q4 = y4[base + 4];
        acc[0] = bl(q.x); acc[1] = bh(q.x);
        acc[2] = bl(q.y); acc[3] = bh(q.y);
        acc[4] = bl(q.z); acc[5] = bh(q.z);
        acc[6] = bl(q.w); acc[7] = bh(q.w);
        acc[8] = bl(q4);  acc[9] = bh(q4);
    }
    int e = rp[c], e1 = rp[c + 1];
    for (; e + 3 < e1; e += 4) {
        long long bA = (long long)srcl[e] * 8;
        long long bB = (long long)srcl[e + 1] * 8;
        long long bC = (long long)srcl[e + 2] * 8;
        long long bD = (long long)srcl[e + 3] * 8;
        uint4 qa = *(const uint4*)(y4 + bA); u32 qa4 = y4[bA + 4];
        uint4 qb = *(const uint4*)(y4 + bB); u32 qb4 = y4[bB + 4];
        uint4 qc = *(const uint4*)(y4 + bC); u32 qc4 = y4[bC + 4];
        uint4 qd = *(const uint4*)(y4 + bD); u32 qd4 = y4[bD + 4];
        acc[0] += (bl(qa.x) + bl(qb.x)) + (bl(qc.x) + bl(qd.x));
        acc[1] += (bh(qa.x) + bh(qb.x)) + (bh(qc.x) + bh(qd.x));
        acc[2] += (bl(qa.y) + bl(qb.y)) + (bl(qc.y) + bl(qd.y));
        acc[3] += (bh(qa.y) + bh(qb.y)) + (bh(qc.y) + bh(qd.y));
        acc[4] += (bl(qa.z) + bl(qb.z)) + (bl(qc.z) + bl(qd.z));
        acc[5] += (bh(qa.z) + bh(qb.z)) + (bh(qc.z) + bh(qd.z));
        acc[6] += (bl(qa.w) + bl(qb.w)) + (bl(qc.w) + bl(qd.w));
        acc[7] += (bh(qa.w) + bh(qb.w)) + (bh(qc.w) + bh(qd.w));
        acc[8] += (bl(qa4) + bl(qb4)) + (bl(qc4) + bl(qd4));
        acc[9] += (bh(qa4) + bh(qb4)) + (bh(qc4) + bh(qd4));
    }
    for (; e < e1; e++) {
        long long bA = (long long)srcl[e] * 8;
        uint4 qa = *(const uint4*)(y4 + bA);
        u32 qa4 = y4[bA + 4];
        acc[0] += bl(qa.x); acc[1] += bh(qa.x);
        acc[2] += bl(qa.y); acc[3] += bh(qa.y);
        acc[4] += bl(qa.z); acc[5] += bh(qa.z);
        acc[6] += bl(qa.w); acc[7] += bh(qa.w);
        acc[8] += bl(qa4);  acc[9] += bh(qa4);
    }
    float d = dis[c];
    float m = -1e30f;
    #pragma unroll
    for (int k = 0; k < 10; k++) {
        acc[k] = fmaf(d, acc[k], bias[k]);
        m = fmaxf(m, acc[k]);
    }
    float s = 0.f;
    #pragma unroll
    for (int k = 0; k < 10; k++) s += expf(acc[k] - m);
    float ls = logf(s);
    #pragma unroll
    for (int k = 0; k < 10; k++) out[(long long)c * 10 + k] = acc[k] - m - ls;
}

// ---------------- MFMA matmul K=128, N=128 ----------------
__global__ __launch_bounds__(256) void mm128_kernel(
    const void* __restrict__ Av, const float* __restrict__ W,
    u32* __restrict__ out, int M,
    const float* __restrict__ dis,
    const u32* __restrict__ gsrc, const int* __restrict__ gidx,
    const float* __restrict__ bias,
    const float* __restrict__ bnscale, const float* __restrict__ bnshift,
    int pool, int afp32)
{
    __shared__ u32 WL[8192];   // [t=8][s=4][lane=64][i=4]
    int tid = threadIdx.x;

    #pragma unroll
    for (int it = 0; it < 32; it++) {
        int flat = it * 256 + tid;
        int i = flat & 3;
        int ln = (flat >> 2) & 63;
        int s = (flat >> 8) & 3;
        int t = flat >> 10;
        int mm = ln & 15, qq = ln >> 4;
        int k0 = s * 32 + qq * 8 + 2 * i;
        int col = t * 16 + mm;
        WL[flat] = pack2(W[k0 * 128 + col], W[(k0 + 1) * 128 + col]);
    }
    __syncthreads();

    int lane = tid & 63;
    int w = tid >> 6;
    int m = lane & 15, q = lane >> 4;
    int row = blockIdx.x * 64 + w * 16 + m;
    bool live = (row < M);

    uint4 xb[4];
    if (live) {
        if (afp32) {
            const float* Af = (const float*)Av;
            #pragma unroll
            for (int s = 0; s < 4; s++) {
                const float4* p = (const float4*)(Af + (long long)row * 128 + s * 32 + q * 8);
                float4 f0 = p[0], f1 = p[1];
                xb[s].x = pack2(f0.x, f0.y);
                xb[s].y = pack2(f0.z, f0.w);
                xb[s].z = pack2(f1.x, f1.y);
                xb[s].w = pack2(f1.z, f1.w);
            }
        } else {
            const u32* Ab = (const u32*)Av;
            #pragma unroll
            for (int s = 0; s < 4; s++)
                xb[s] = *(const uint4*)(Ab + (long long)row * 64 + s * 16 + q * 4);
        }
    } else {
        xb[0] = xb[1] = xb[2] = xb[3] = make_uint4(0u, 0u, 0u, 0u);
    }

    float d = 1.0f;
    if (dis && live) d = dis[row];
    long long gbase = (gsrc && live) ? (long long)gidx[row] * 64 : 0;

    #pragma unroll
    for (int t = 0; t < 8; t++) {
        f32x4 acc = {0.f, 0.f, 0.f, 0.f};
        #pragma unroll
        for (int s = 0; s < 4; s++) {
            uint4 wa = *(const uint4*)&WL[((t * 4 + s) * 64 + lane) * 4];
            acc = __builtin_amdgcn_mfma_f32_16x16x32_bf16(asbf(wa), asbf(xb[s]), acc, 0, 0, 0);
        }
        if (live) {
            float v0 = acc[0], v1 = acc[1], v2 = acc[2], v3 = acc[3];
            int cbase = t * 16 + q * 4;
            if (gsrc) {
                uint2 g = *(const uint2*)(gsrc + gbase + (cbase >> 1));
                v0 += bl(g.x); v1 += bh(g.x);
                v2 += bl(g.y); v3 += bh(g.y);
            }
            if (pool) {
                float4 bb = *(const float4*)(bias + cbase);
                float4 sc = *(const float4*)(bnscale + cbase);
                float4 sh = *(const float4*)(bnshift + cbase);
                v0 = fmaxf(fmaxf(v0 + bb.x, 0.f) * sc.x + sh.x, 0.f);
                v1 = fmaxf(fmaxf(v1 + bb.y, 0.f) * sc.y + sh.y, 0.f);
                v2 = fmaxf(fmaxf(v2 + bb.z, 0.f) * sc.z + sh.z, 0.f);
                v3 = fmaxf(fmaxf(v3 + bb.w, 0.f) * sc.w + sh.w, 0.f);
            }
            v0 *= d; v1 *= d; v2 *= d; v3 *= d;
            uint2 st;
            st.x = pack2(v0, v1);
            st.y = pack2(v2, v3);
            *(uint2*)(out + (long long)row * 64 + (cbase >> 1)) = st;
        }
    }
}

// ---------------- matmul K=128, N=10 ----------------
__global__ __launch_bounds__(256) void mm10_kernel(
    const u32* __restrict__ A, const float* __restrict__ W,
    float* __restrict__ out, int M)
{
    __shared__ float Ws[128 * 10];
    for (int i = threadIdx.x; i < 1280; i += 256) Ws[i] = W[i];
    __syncthreads();
    int row = blockIdx.x * blockDim.x + threadIdx.x;
    if (row >= M) return;
    const uint4* a = (const uint4*)(A + (long long)row * 64);
    float acc[10] = {0, 0, 0, 0, 0, 0, 0, 0, 0, 0};
    #pragma unroll 4
    for (int i = 0; i < 16; i++) {
        uint4 av = a[i];
        int k = i * 8;
        float f[8] = { bl(av.x), bh(av.x), bl(av.y), bh(av.y),
                       bl(av.z), bh(av.z), bl(av.w), bh(av.w) };
        #pragma unroll
        for (int j = 0; j < 8; j++) {
            #pragma unroll
            for (int cc = 0; cc < 10; cc++)
                acc[cc] += f[j] * Ws[(k + j) * 10 + cc];
        }
    }
    #pragma unroll
    for (int cc = 0; cc < 10; cc++) out[(long long)row * 10 + cc] = acc[cc];
}

__global__ __launch_bounds__(256) void mm10p_kernel(
    const u32* __restrict__ A, const float* __restrict__ W,
    u32* __restrict__ outp, int M,
    const float* __restrict__ dis,
    const float* __restrict__ gsrc, const int* __restrict__ gidx)
{
    __shared__ float Ws[128 * 10];
    for (int i = threadIdx.x; i < 1280; i += 256) Ws[i] = W[i];
    __syncthreads();
    int row = blockIdx.x * blockDim.x + threadIdx.x;
    if (row >= M) return;
    const uint4* a = (const uint4*)(A + (long long)row * 64);
    float acc[10] = {0, 0, 0, 0, 0, 0, 0, 0, 0, 0};
    #pragma unroll 4
    for (int i = 0; i < 16; i++) {
        uint4 av = a[i];
        int k = i * 8;
        float f[8] = { bl(av.x), bh(av.x), bl(av.y), bh(av.y),
                       bl(av.z), bh(av.z), bl(av.w), bh(av.w) };
        #pragma unroll
        for (int j = 0; j < 8; j++) {
            #pragma unroll
            for (int cc = 0; cc < 10; cc++)
                acc[cc] += f[j] * Ws[(k + j) * 10 + cc];
        }
    }
    float d = dis[row];
    const float* g = gsrc + (long long)gidx[row] * 10;
    long long base = (long long)row * 8;
    #pragma unroll
    for (int j = 0; j < 5; j++) {
        float v0 = (acc[2 * j] + g[2 * j]) * d;
        float v1 = (acc[2 * j + 1] + g[2 * j + 1]) * d;
        outp[base + j] = pack2(v0, v1);
    }
}

// ---------------- launcher ----------------

extern "C" void kernel_launch(void* const* d_in, const int* in_sizes, int n_in,
                              void* d_out, int out_size, void* d_ws, size_t ws_size,
                              hipStream_t stream) {
    const float* x       = (const float*)d_in[0];
    const int*   ei0     = (const int*)d_in[1];
    const int*   ei1     = (const int*)d_in[2];
    const int*   ei2     = (const int*)d_in[3];
    const int*   parent1 = (const int*)d_in[4];
    const int*   parent2 = (const int*)d_in[5];
    const float* W0 = (const float*)d_in[6];
    const float* b0 = (const float*)d_in[7];
    const float* W1 = (const float*)d_in[8];
    const float* b1 = (const float*)d_in[9];
    const float* W2 = (const float*)d_in[10];
    const float* b2 = (const float*)d_in[11];
    const float* W3 = (const float*)d_in[12];
    const float* b3 = (const float*)d_in[13];
    const float* W4 = (const float*)d_in[14];
    const float* b4 = (const float*)d_in[15];
    const float* pW = (const float*)d_in[16];
    const float* pb = (const float*)d_in[17];
    const float* pg = (const float*)d_in[18];
    const float* pbeta = (const float*)d_in[19];
    const float* pmean = (const float*)d_in[20];
    const float* pvar  = (const float*)d_in[21];
    float* out = (float*)d_out;

    char* ws = (char*)d_ws;
    size_t off = 0;
    auto alloc = [&](size_t nbytes) -> char* {
        char* p = ws + off;
        off += ((nbytes + 255) / 256) * 256;
        return p;
    };
    float* dis0 = (float*)alloc(N0 * 4);
    float* dis1 = (float*)alloc(N1 * 4);
    float* dis2 = (float*)alloc(N2 * 4);
    float* bnscale = (float*)alloc(4 * HDIM * 4);
    float* bnshift = (float*)alloc(4 * HDIM * 4);
    float* W1b = (float*)alloc((size_t)N1 * 10 * 4);
    u32* Y   = (u32*)alloc((size_t)N0 * 64 * 4);
    u32* H0  = (u32*)alloc((size_t)N0 * 64 * 4);
    u32* H1  = (u32*)alloc((size_t)N1 * 64 * 4);
    u32* P   = (u32*)alloc((size_t)N1 * 64 * 4);
    u32* X1  = (u32*)alloc((size_t)N1 * 64 * 4);
    u32* HU1 = (u32*)alloc((size_t)N1 * 64 * 4);
    u32* U1  = (u32*)alloc((size_t)N1 * 64 * 4);
    u32* X2  = (u32*)alloc((size_t)N2 * 64 * 4);
    u32* H2  = (u32*)alloc((size_t)N2 * 64 * 4);
    u32* U2  = (u32*)alloc((size_t)N2 * 64 * 4);
    u32* V2  = (u32*)alloc((size_t)N2 * 64 * 4);
    u32* Y4p = (u32*)alloc((size_t)N0 * 8 * 4);
    int* rpAll = (int*)alloc((size_t)(OFFT + 1) * 4);
    int* srcU  = (int*)alloc((size_t)S4 * 4);
    int* blockHist = (int*)alloc((size_t)BH_N * 4);
    int* OfsAbs    = (int*)alloc((size_t)(BH_N + 1) * 4);
    u32* binPair   = (u32*)alloc((size_t)S4 * 4);
    int* bsum   = (int*)alloc(NBLK2 * 4);
    int* totalb = (int*)alloc(4);

    const int B = 256;
    auto G = [](long long t) { return (unsigned)((t + 255) / 256); };
    auto G64 = [](long long m) { return (unsigned)((m + 63) / 64); };

    // ---- CSR build ----
    binhist_kernel<<<NBA, B, 0, stream>>>(
        ei0 + E0C, ei1 + E1C, ei2 + E2C, parent1, parent2, blockHist);
    scan_k1<<<NBLK2, B, 0, stream>>>(blockHist, bsum, BH_N);
    scan_k2<<<1, B, 0, stream>>>(bsum, totalb, NBLK2);
    scan_k3<<<NBLK2, B, 0, stream>>>(blockHist, bsum, totalb, OfsAbs, BH_N);
    binfill_kernel<<<NBA, B, 0, stream>>>(
        ei0, ei0 + E0C, ei1, ei1 + E1C, ei2, ei2 + E2C, parent1, parent2, OfsAbs, binPair);
    bucket_build_kernel<<<NBUCK, B, 0, stream>>>(
        binPair, OfsAbs, rpAll, srcU, dis0, dis1, dis2);
    bn_pre_kernel<<<2, B, 0, stream>>>(pg, pbeta, pmean, pvar, bnscale, bnshift);

    // ---- gcn0 ----
    mm128_kernel<<<G64(N0), B, 0, stream>>>(
        x, W0, Y, N0, dis0, nullptr, nullptr, nullptr, nullptr, nullptr, 0, 1);
    gather128_kernel<<<G((long long)N0 * 64), B, 0, stream>>>(rpAll + OFF0, srcU, Y, dis0, b0, H0, N0);

    // ---- pool1 ----
    gatherP_kernel<<<G((long long)N1 * 64), B, 0, stream>>>(rpAll + OFF3, srcU, H0, P, N1);
    mm128_kernel<<<G64(N1), B, 0, stream>>>(
        P, pW, X1, N1, nullptr, nullptr, nullptr, pb, bnscale, bnshift, 1, 0);

    // ---- gcn1 ----
    mm128_kernel<<<G64(N1), B, 0, stream>>>(
        X1, W1, Y, N1, dis1, nullptr, nullptr, nullptr, nullptr, nullptr, 0, 0);
    gather128_kernel<<<G((long long)N1 * 64), B, 0, stream>>>(rpAll + OFF1, srcU, Y, dis1, b1, H1, N1);

    // ---- pool2 ----
    gatherP_kernel<<<G((long long)N2 * 64), B, 0, stream>>>(rpAll + OFF4, srcU, H1, P, N2);
    mm128_kernel<<<G64(N2), B, 0, stream>>>(
        P, pW + 128 * 128, X2, N2, nullptr, nullptr, nullptr, pb + 128, bnscale + 128, bnshift + 128, 1, 0);

    // ---- gcn2 ----
    mm128_kernel<<<G64(N2), B, 0, stream>>>(
        X2, W2, Y, N2, dis2, nullptr, nullptr, nullptr, nullptr, nullptr, 0, 0);
    gather128_kernel<<<G((long long)N2 * 64), B, 0, stream>>>(rpAll + OFF2, srcU, Y, dis2, b2, H2, N2);

    // ---- up level 2 ----
    mm128_kernel<<<G64(N2), B, 0, stream>>>(
        H2, pW + 2 * 128 * 128, U2, N2, nullptr, nullptr, nullptr, pb + 256, bnscale + 256, bnshift + 256, 1, 0);
    mm128_kernel<<<G64(N2), B, 0, stream>>>(
        U2, W3, V2, N2, nullptr, nullptr, nullptr, nullptr, nullptr, nullptr, 0, 0);

    // ---- gcn3 ----
    mm128_kernel<<<G64(N1), B, 0, stream>>>(
        H1, W3 + 128 * 128, Y, N1, dis1, V2, parent2, nullptr, nullptr, nullptr, 0, 0);
    gather128_kernel<<<G((long long)N1 * 64), B, 0, stream>>>(rpAll + OFF1, srcU, Y, dis1, b3, HU1, N1);

    // ---- up level 1 ----
    mm128_kernel<<<G64(N1), B, 0, stream>>>(
        HU1, pW + 3 * 128 * 128, U1, N1, nullptr, nullptr, nullptr, pb + 384, bnscale + 384, bnshift + 384, 1, 0);
    mm10_kernel<<<G(N1), B, 0, stream>>>(U1, W4, W1b, N1);

    // ---- gcn4 ----
    mm10p_kernel<<<G(N0), B, 0, stream>>>(H0, W4 + 128 * 10, Y4p, N0, dis0, W1b, parent1);
    gather10_lsm_kernel<<<G(N0), B, 0, stream>>>(rpAll + OFF0, srcU, Y4p, dis0, b4, out, N0);
}

// Round 15
// 431.798 us; speedup vs baseline: 1.2267x; 1.0361x over previous
//
#include <hip/hip_runtime.h>
#include <math.h>

#define N0 100000
#define N1 20000
#define N2 4000
#define HDIM 128
#define E0C 1600000
#define E1C 320000
#define E2C 64000
#define EPSBN 1e-5f

typedef unsigned int u32;
typedef float f32x4 __attribute__((ext_vector_type(4)));
typedef short bf16x8 __attribute__((ext_vector_type(8)));

union FragU { uint4 u; bf16x8 h; };
__device__ __forceinline__ bf16x8 asbf(uint4 v) { FragU x; x.u = v; return x.h; }

__device__ __forceinline__ float bl(u32 p) { return __uint_as_float(p << 16); }
__device__ __forceinline__ float bh(u32 p) { return __uint_as_float(p & 0xFFFF0000u); }
__device__ __forceinline__ u32 pack2(float a, float b) {
    u32 ua = __float_as_uint(a), ub = __float_as_uint(b);
    ua = (ua + 0x7FFFu + ((ua >> 16) & 1u)) >> 16;
    ub = (ub + 0x7FFFu + ((ub >> 16) & 1u)) >> 16;
    return ua | (ub << 16);
}

// concatenated destination space
#define OFF0 0
#define OFF1 (N0)
#define OFF2 (N0 + N1)
#define OFF3 (N0 + N1 + N2)
#define OFF4 (N0 + N1 + N2 + N1)
#define OFFT (N0 + N1 + N2 + N1 + N2)        // 148000

// concatenated work items
#define S0 (E0C)
#define S1 (E0C + E1C)
#define S2 (E0C + E1C + E2C)
#define S3 (E0C + E1C + E2C + N0)
#define S4 (E0C + E1C + E2C + N0 + N1)       // 2,104,000

// counting-sort geometry
#define NBUCK ((OFFT + 1023) / 1024)         // 145 coarse buckets
#define ITEMS_PER_BLK 2048
#define NBA ((S4 + ITEMS_PER_BLK - 1) / ITEMS_PER_BLK)   // 1028 blocks
#define BH_N (NBUCK * NBA)
#define NBLK2 ((BH_N + 1023) / 1024)

// ---------------- CSR build (LDS counting sort, zero global atomics) ----------------
// binPair entry: (concat&1023)<<17 | payload   (payload < 2^17, bucket implied by position)

__device__ __forceinline__ void item_full(int g,
    const int* __restrict__ ei0r, const int* __restrict__ ei0c,
    const int* __restrict__ ei1r, const int* __restrict__ ei1c,
    const int* __restrict__ ei2r, const int* __restrict__ ei2c,
    const int* __restrict__ p1, const int* __restrict__ p2,
    int& concat, int& payload)
{
    if (g < S0)      { concat = ei0c[g];             payload = ei0r[g]; }
    else if (g < S1) { int i = g - S0; concat = OFF1 + ei1c[i]; payload = ei1r[i]; }
    else if (g < S2) { int i = g - S1; concat = OFF2 + ei2c[i]; payload = ei2r[i]; }
    else if (g < S3) { int i = g - S2; concat = OFF3 + p1[i];   payload = i; }
    else             { int i = g - S3; concat = OFF4 + p2[i];   payload = i; }
}

__device__ __forceinline__ int item_concat(int g,
    const int* __restrict__ ei0c, const int* __restrict__ ei1c, const int* __restrict__ ei2c,
    const int* __restrict__ p1, const int* __restrict__ p2)
{
    if (g < S0)      return ei0c[g];
    else if (g < S1) return OFF1 + ei1c[g - S0];
    else if (g < S2) return OFF2 + ei2c[g - S1];
    else if (g < S3) return OFF3 + p1[g - S2];
    else             return OFF4 + p2[g - S3];
}

__global__ __launch_bounds__(256) void binhist_kernel(
    const int* __restrict__ ei0c, const int* __restrict__ ei1c, const int* __restrict__ ei2c,
    const int* __restrict__ p1, const int* __restrict__ p2,
    int* __restrict__ blockHist)
{
    __shared__ int hist[NBUCK];
    int tid = threadIdx.x, blk = blockIdx.x;
    for (int i = tid; i < NBUCK; i += 256) hist[i] = 0;
    __syncthreads();
    int base = blk * ITEMS_PER_BLK;
    #pragma unroll
    for (int k = 0; k < ITEMS_PER_BLK / 256; k++) {
        int g = base + k * 256 + tid;
        if (g < S4) {
            int c = item_concat(g, ei0c, ei1c, ei2c, p1, p2);
            atomicAdd(&hist[c >> 10], 1);
        }
    }
    __syncthreads();
    for (int b = tid; b < NBUCK; b += 256) blockHist[b * NBA + blk] = hist[b];
}

__global__ __launch_bounds__(256) void scan_k1(const int* __restrict__ c, int* __restrict__ bsum, int n) {
    int t = threadIdx.x;
    int base = blockIdx.x * 1024 + t * 4;
    int s = 0;
    #pragma unroll
    for (int j = 0; j < 4; j++) {
        int idx = base + j;
        if (idx < n) s += c[idx];
    }
    #pragma unroll
    for (int o = 32; o > 0; o >>= 1) s += __shfl_down(s, o, 64);
    __shared__ int ws[4];
    if ((t & 63) == 0) ws[t >> 6] = s;
    __syncthreads();
    if (t == 0) bsum[blockIdx.x] = ws[0] + ws[1] + ws[2] + ws[3];
}

__global__ __launch_bounds__(256) void scan_k2(int* __restrict__ bsum, int* __restrict__ totalOut, int nb) {
    int t = threadIdx.x;
    int v = (t < nb) ? bsum[t] : 0;
    __shared__ int ts[256];
    ts[t] = v;
    __syncthreads();
    for (int o = 1; o < 256; o <<= 1) {
        int u = (t >= o) ? ts[t - o] : 0;
        __syncthreads();
        ts[t] += u;
        __syncthreads();
    }
    if (t < nb) bsum[t] = ts[t] - v;
    if (t == nb - 1) *totalOut = ts[t];
}

__global__ __launch_bounds__(256) void scan_k3(const int* __restrict__ c, const int* __restrict__ bsum,
                                               const int* __restrict__ total,
                                               int* __restrict__ S, int n) {
    int t = threadIdx.x;
    int base = blockIdx.x * 1024 + t * 4;
    int v[4];
    #pragma unroll
    for (int j = 0; j < 4; j++) v[j] = (base + j < n) ? c[base + j] : 0;
    int tsum = v[0] + v[1] + v[2] + v[3];
    __shared__ int ts[256];
    ts[t] = tsum;
    __syncthreads();
    for (int o = 1; o < 256; o <<= 1) {
        int u = (t >= o) ? ts[t - o] : 0;
        __syncthreads();
        ts[t] += u;
        __syncthreads();
    }
    int run = bsum[blockIdx.x] + ts[t] - tsum;
    #pragma unroll
    for (int j = 0; j < 4; j++) {
        if (base + j < n) { S[base + j] = run; run += v[j]; }
    }
    if (blockIdx.x == 0 && t == 0) S[n] = *total;
}

__global__ __launch_bounds__(256) void binfill_kernel(
    const int* __restrict__ ei0r, const int* __restrict__ ei0c,
    const int* __restrict__ ei1r, const int* __restrict__ ei1c,
    const int* __restrict__ ei2r, const int* __restrict__ ei2c,
    const int* __restrict__ p1, const int* __restrict__ p2,
    const int* __restrict__ OfsAbs, u32* __restrict__ binPair)
{
    __shared__ int cur[NBUCK];
    int tid = threadIdx.x, blk = blockIdx.x;
    for (int i = tid; i < NBUCK; i += 256) cur[i] = OfsAbs[i * NBA + blk];
    __syncthreads();
    int base = blk * ITEMS_PER_BLK;
    #pragma unroll
    for (int k = 0; k < ITEMS_PER_BLK / 256; k++) {
        int g = base + k * 256 + tid;
        if (g < S4) {
            int c, p;
            item_full(g, ei0r, ei0c, ei1r, ei1c, ei2r, ei2c, p1, p2, c, p);
            int pos = atomicAdd(&cur[c >> 10], 1);
            binPair[pos] = ((u32)(c & 1023) << 17) | (u32)p;
        }
    }
}

__global__ __launch_bounds__(1024) void bucket_build_kernel(
    const u32* __restrict__ binPair, const int* __restrict__ OfsAbs,
    int* __restrict__ rpAll, int* __restrict__ srcU,
    float* __restrict__ dis0, float* __restrict__ dis1, float* __restrict__ dis2)
{
    __shared__ int cnt_l[1024];
    __shared__ int rp_l[1024];
    __shared__ int ts2[1024];
    int b = blockIdx.x, tid = threadIdx.x;
    int start = OfsAbs[b * NBA];
    int end = (b + 1 < NBUCK) ? OfsAbs[(b + 1) * NBA] : S4;
    int d0 = b << 10;
    int nd = OFFT - d0; if (nd > 1024) nd = 1024;

    cnt_l[tid] = 0;
    __syncthreads();
    for (int i = start + tid; i < end; i += 1024) {
        u32 e = binPair[i];
        atomicAdd(&cnt_l[e >> 17], 1);
    }
    __syncthreads();
    int v = cnt_l[tid];
    ts2[tid] = v;
    __syncthreads();
    for (int o = 1; o < 1024; o <<= 1) {
        int u = (tid >= o) ? ts2[tid - o] : 0;
        __syncthreads();
        ts2[tid] += u;
        __syncthreads();
    }
    rp_l[tid] = ts2[tid] - v;   // exclusive scan
    __syncthreads();
    if (tid < nd) {
        int g = d0 + tid;
        rpAll[g] = start + rp_l[tid];
        float dv = rsqrtf((float)(v + 1));
        if (g < OFF1) dis0[g] = dv;
        else if (g < OFF2) dis1[g - OFF1] = dv;
        else if (g < OFF3) dis2[g - OFF2] = dv;
    }
    if (b == NBUCK - 1 && tid == 0) rpAll[OFFT] = S4;
    __syncthreads();
    for (int i = start + tid; i < end; i += 1024) {
        u32 e = binPair[i];
        int pos = start + atomicAdd(&rp_l[e >> 17], 1);
        srcU[pos] = (int)(e & 0x1FFFFu);
    }
}

__global__ void bn_pre_kernel(const float* __restrict__ g, const float* __restrict__ beta,
                              const float* __restrict__ mean, const float* __restrict__ var,
                              float* __restrict__ scale, float* __restrict__ shift) {
    int i = blockIdx.x * blockDim.x + threadIdx.x;
    if (i < 4 * HDIM) {
        float s = g[i] * rsqrtf(var[i] + EPSBN);
        scale[i] = s;
        shift[i] = beta[i] - mean[i] * s;
    }
}

// ---------------- gather kernels (bf16 features, fp32 accumulate) ----------------

#define G128_LOAD(sym, off) u32 sym = y[(long long)srcl[e + off] * 64 + lane]

__global__ __launch_bounds__(256) void gather128_kernel(
    const int* __restrict__ rp, const int* __restrict__ srcl,
    const u32* __restrict__ y, const float* __restrict__ dis,
    const float* __restrict__ bias, u32* __restrict__ h, int n)
{
    int wid = (int)((blockIdx.x * 256 + threadIdx.x) >> 6);
    int lane = threadIdx.x & 63;
    if (wid >= n) return;
    u32 self = y[(long long)wid * 64 + lane];
    float ax = bl(self), ay = bh(self);
    int e = rp[wid], e1 = rp[wid + 1];
    for (; e + 7 < e1; e += 8) {
        G128_LOAD(p0, 0); G128_LOAD(p1, 1); G128_LOAD(p2, 2); G128_LOAD(p3, 3);
        G128_LOAD(p4, 4); G128_LOAD(p5, 5); G128_LOAD(p6, 6); G128_LOAD(p7, 7);
        ax += ((bl(p0) + bl(p1)) + (bl(p2) + bl(p3))) + ((bl(p4) + bl(p5)) + (bl(p6) + bl(p7)));
        ay += ((bh(p0) + bh(p1)) + (bh(p2) + bh(p3))) + ((bh(p4) + bh(p5)) + (bh(p6) + bh(p7)));
    }
    if (e + 3 < e1) {
        G128_LOAD(p0, 0); G128_LOAD(p1, 1); G128_LOAD(p2, 2); G128_LOAD(p3, 3);
        ax += (bl(p0) + bl(p1)) + (bl(p2) + bl(p3));
        ay += (bh(p0) + bh(p1)) + (bh(p2) + bh(p3));
        e += 4;
    }
    if (e + 1 < e1) {
        G128_LOAD(p0, 0); G128_LOAD(p1, 1);
        ax += bl(p0) + bl(p1);
        ay += bh(p0) + bh(p1);
        e += 2;
    }
    if (e < e1) {
        G128_LOAD(p0, 0);
        ax += bl(p0); ay += bh(p0);
    }
    float d = dis[wid];
    float2 b = ((const float2*)bias)[lane];
    float r0 = fmaxf(fmaf(d, ax, b.x), 0.f);
    float r1 = fmaxf(fmaf(d, ay, b.y), 0.f);
    h[(long long)wid * 64 + lane] = pack2(r0, r1);
}

__global__ __launch_bounds__(256) void gather10_lsm_kernel(
    const int* __restrict__ rp, const int* __restrict__ srcl,
    const u32* __restrict__ y4, const float* __restrict__ dis,
    const float* __restrict__ bias, float* __restrict__ out, int n)
{
    int c = blockIdx.x * blockDim.x + threadIdx.x;
    if (c >= n) return;
    float acc[10];
    {
        long long base = (long long)c * 8;
        uint4 q = *(const uint4*)(y4 + base);
        u32 q4 = y4[base + 4];
        acc[0] = bl(q.x); acc[1] = bh(q.x);
        acc[2] = bl(q.y); acc[3] = bh(q.y);
        acc[4] = bl(q.z); acc[5] = bh(q.z);
        acc[6] = bl(q.w); acc[7] = bh(q.w);
        acc[8] = bl(q4);  acc[9] = bh(q4);
    }
    int e = rp[c], e1 = rp[c + 1];
    for (; e + 3 < e1; e += 4) {
        long long bA = (long long)srcl[e] * 8;
        long long bB = (long long)srcl[e + 1] * 8;
        long long bC = (long long)srcl[e + 2] * 8;
        long long bD = (long long)srcl[e + 3] * 8;
        uint4 qa = *(const uint4*)(y4 + bA); u32 qa4 = y4[bA + 4];
        uint4 qb = *(const uint4*)(y4 + bB); u32 qb4 = y4[bB + 4];
        uint4 qc = *(const uint4*)(y4 + bC); u32 qc4 = y4[bC + 4];
        uint4 qd = *(const uint4*)(y4 + bD); u32 qd4 = y4[bD + 4];
        acc[0] += (bl(qa.x) + bl(qb.x)) + (bl(qc.x) + bl(qd.x));
        acc[1] += (bh(qa.x) + bh(qb.x)) + (bh(qc.x) + bh(qd.x));
        acc[2] += (bl(qa.y) + bl(qb.y)) + (bl(qc.y) + bl(qd.y));
        acc[3] += (bh(qa.y) + bh(qb.y)) + (bh(qc.y) + bh(qd.y));
        acc[4] += (bl(qa.z) + bl(qb.z)) + (bl(qc.z) + bl(qd.z));
        acc[5] += (bh(qa.z) + bh(qb.z)) + (bh(qc.z) + bh(qd.z));
        acc[6] += (bl(qa.w) + bl(qb.w)) + (bl(qc.w) + bl(qd.w));
        acc[7] += (bh(qa.w) + bh(qb.w)) + (bh(qc.w) + bh(qd.w));
        acc[8] += (bl(qa4) + bl(qb4)) + (bl(qc4) + bl(qd4));
        acc[9] += (bh(qa4) + bh(qb4)) + (bh(qc4) + bh(qd4));
    }
    for (; e < e1; e++) {
        long long bA = (long long)srcl[e] * 8;
        uint4 qa = *(const uint4*)(y4 + bA);
        u32 qa4 = y4[bA + 4];
        acc[0] += bl(qa.x); acc[1] += bh(qa.x);
        acc[2] += bl(qa.y); acc[3] += bh(qa.y);
        acc[4] += bl(qa.z); acc[5] += bh(qa.z);
        acc[6] += bl(qa.w); acc[7] += bh(qa.w);
        acc[8] += bl(qa4);  acc[9] += bh(qa4);
    }
    float d = dis[c];
    float m = -1e30f;
    #pragma unroll
    for (int k = 0; k < 10; k++) {
        acc[k] = fmaf(d, acc[k], bias[k]);
        m = fmaxf(m, acc[k]);
    }
    float s = 0.f;
    #pragma unroll
    for (int k = 0; k < 10; k++) s += expf(acc[k] - m);
    float ls = logf(s);
    #pragma unroll
    for (int k = 0; k < 10; k++) out[(long long)c * 10 + k] = acc[k] - m - ls;
}

// ---------------- MFMA matmul K=128, N=128 ----------------
// apool=1: A-row fragments are segment sums of child rows of Av (bf16) per pp/childl
__global__ __launch_bounds__(256) void mm128_kernel(
    const void* __restrict__ Av, const float* __restrict__ W,
    u32* __restrict__ out, int M,
    const float* __restrict__ dis,
    const u32* __restrict__ gsrc, const int* __restrict__ gidx,
    const float* __restrict__ bias,
    const float* __restrict__ bnscale, const float* __restrict__ bnshift,
    int pool, int afp32,
    const int* __restrict__ pp, const int* __restrict__ childl, int apool)
{
    __shared__ u32 WL[8192];   // [t=8][s=4][lane=64][i=4]
    int tid = threadIdx.x;

    #pragma unroll
    for (int it = 0; it < 32; it++) {
        int flat = it * 256 + tid;
        int i = flat & 3;
        int ln = (flat >> 2) & 63;
        int s = (flat >> 8) & 3;
        int t = flat >> 10;
        int mm = ln & 15, qq = ln >> 4;
        int k0 = s * 32 + qq * 8 + 2 * i;
        int col = t * 16 + mm;
        WL[flat] = pack2(W[k0 * 128 + col], W[(k0 + 1) * 128 + col]);
    }
    __syncthreads();

    int lane = tid & 63;
    int w = tid >> 6;
    int m = lane & 15, q = lane >> 4;
    int row = blockIdx.x * 64 + w * 16 + m;
    bool live = (row < M);

    uint4 xb[4];
    if (live) {
        if (apool) {
            float fa[32];
            #pragma unroll
            for (int i = 0; i < 32; i++) fa[i] = 0.f;
            const u32* Hb = (const u32*)Av;
            int e = pp[row], eE = pp[row + 1];
            for (; e < eE; e++) {
                long long cb = (long long)childl[e] * 64;
                #pragma unroll
                for (int s = 0; s < 4; s++) {
                    uint4 vv = *(const uint4*)(Hb + cb + s * 16 + q * 4);
                    fa[s * 8 + 0] += bl(vv.x); fa[s * 8 + 1] += bh(vv.x);
                    fa[s * 8 + 2] += bl(vv.y); fa[s * 8 + 3] += bh(vv.y);
                    fa[s * 8 + 4] += bl(vv.z); fa[s * 8 + 5] += bh(vv.z);
                    fa[s * 8 + 6] += bl(vv.w); fa[s * 8 + 7] += bh(vv.w);
                }
            }
            #pragma unroll
            for (int s = 0; s < 4; s++) {
                xb[s].x = pack2(fa[s * 8 + 0], fa[s * 8 + 1]);
                xb[s].y = pack2(fa[s * 8 + 2], fa[s * 8 + 3]);
                xb[s].z = pack2(fa[s * 8 + 4], fa[s * 8 + 5]);
                xb[s].w = pack2(fa[s * 8 + 6], fa[s * 8 + 7]);
            }
        } else if (afp32) {
            const float* Af = (const float*)Av;
            #pragma unroll
            for (int s = 0; s < 4; s++) {
                const float4* p = (const float4*)(Af + (long long)row * 128 + s * 32 + q * 8);
                float4 f0 = p[0], f1 = p[1];
                xb[s].x = pack2(f0.x, f0.y);
                xb[s].y = pack2(f0.z, f0.w);
                xb[s].z = pack2(f1.x, f1.y);
                xb[s].w = pack2(f1.z, f1.w);
            }
        } else {
            const u32* Ab = (const u32*)Av;
            #pragma unroll
            for (int s = 0; s < 4; s++)
                xb[s] = *(const uint4*)(Ab + (long long)row * 64 + s * 16 + q * 4);
        }
    } else {
        xb[0] = xb[1] = xb[2] = xb[3] = make_uint4(0u, 0u, 0u, 0u);
    }

    float d = 1.0f;
    if (dis && live) d = dis[row];
    long long gbase = (gsrc && live) ? (long long)gidx[row] * 64 : 0;

    #pragma unroll
    for (int t = 0; t < 8; t++) {
        f32x4 acc = {0.f, 0.f, 0.f, 0.f};
        #pragma unroll
        for (int s = 0; s < 4; s++) {
            uint4 wa = *(const uint4*)&WL[((t * 4 + s) * 64 + lane) * 4];
            acc = __builtin_amdgcn_mfma_f32_16x16x32_bf16(asbf(wa), asbf(xb[s]), acc, 0, 0, 0);
        }
        if (live) {
            float v0 = acc[0], v1 = acc[1], v2 = acc[2], v3 = acc[3];
            int cbase = t * 16 + q * 4;
            if (gsrc) {
                uint2 g = *(const uint2*)(gsrc + gbase + (cbase >> 1));
                v0 += bl(g.x); v1 += bh(g.x);
                v2 += bl(g.y); v3 += bh(g.y);
            }
            if (pool) {
                float4 bb = *(const float4*)(bias + cbase);
                float4 sc = *(const float4*)(bnscale + cbase);
                float4 sh = *(const float4*)(bnshift + cbase);
                v0 = fmaxf(fmaxf(v0 + bb.x, 0.f) * sc.x + sh.x, 0.f);
                v1 = fmaxf(fmaxf(v1 + bb.y, 0.f) * sc.y + sh.y, 0.f);
                v2 = fmaxf(fmaxf(v2 + bb.z, 0.f) * sc.z + sh.z, 0.f);
                v3 = fmaxf(fmaxf(v3 + bb.w, 0.f) * sc.w + sh.w, 0.f);
            }
            v0 *= d; v1 *= d; v2 *= d; v3 *= d;
            uint2 st;
            st.x = pack2(v0, v1);
            st.y = pack2(v2, v3);
            *(uint2*)(out + (long long)row * 64 + (cbase >> 1)) = st;
        }
    }
}

// ---------------- matmul K=128, N=10 ----------------
__global__ __launch_bounds__(256) void mm10_kernel(
    const u32* __restrict__ A, const float* __restrict__ W,
    float* __restrict__ out, int M)
{
    __shared__ float Ws[128 * 10];
    for (int i = threadIdx.x; i < 1280; i += 256) Ws[i] = W[i];
    __syncthreads();
    int row = blockIdx.x * blockDim.x + threadIdx.x;
    if (row >= M) return;
    const uint4* a = (const uint4*)(A + (long long)row * 64);
    float acc[10] = {0, 0, 0, 0, 0, 0, 0, 0, 0, 0};
    #pragma unroll 4
    for (int i = 0; i < 16; i++) {
        uint4 av = a[i];
        int k = i * 8;
        float f[8] = { bl(av.x), bh(av.x), bl(av.y), bh(av.y),
                       bl(av.z), bh(av.z), bl(av.w), bh(av.w) };
        #pragma unroll
        for (int j = 0; j < 8; j++) {
            #pragma unroll
            for (int cc = 0; cc < 10; cc++)
                acc[cc] += f[j] * Ws[(k + j) * 10 + cc];
        }
    }
    #pragma unroll
    for (int cc = 0; cc < 10; cc++) out[(long long)row * 10 + cc] = acc[cc];
}

__global__ __launch_bounds__(256) void mm10p_kernel(
    const u32* __restrict__ A, const float* __restrict__ W,
    u32* __restrict__ outp, int M,
    const float* __restrict__ dis,
    const float* __restrict__ gsrc, const int* __restrict__ gidx)
{
    __shared__ float Ws[128 * 10];
    for (int i = threadIdx.x; i < 1280; i += 256) Ws[i] = W[i];
    __syncthreads();
    int row = blockIdx.x * blockDim.x + threadIdx.x;
    if (row >= M) return;
    const uint4* a = (const uint4*)(A + (long long)row * 64);
    float acc[10] = {0, 0, 0, 0, 0, 0, 0, 0, 0, 0};
    #pragma unroll 4
    for (int i = 0; i < 16; i++) {
        uint4 av = a[i];
        int k = i * 8;
        float f[8] = { bl(av.x), bh(av.x), bl(av.y), bh(av.y),
                       bl(av.z), bh(av.z), bl(av.w), bh(av.w) };
        #pragma unroll
        for (int j = 0; j < 8; j++) {
            #pragma unroll
            for (int cc = 0; cc < 10; cc++)
                acc[cc] += f[j] * Ws[(k + j) * 10 + cc];
        }
    }
    float d = dis[row];
    const float* g = gsrc + (long long)gidx[row] * 10;
    long long base = (long long)row * 8;
    #pragma unroll
    for (int j = 0; j < 5; j++) {
        float v0 = (acc[2 * j] + g[2 * j]) * d;
        float v1 = (acc[2 * j + 1] + g[2 * j + 1]) * d;
        outp[base + j] = pack2(v0, v1);
    }
}

// ---------------- launcher ----------------

extern "C" void kernel_launch(void* const* d_in, const int* in_sizes, int n_in,
                              void* d_out, int out_size, void* d_ws, size_t ws_size,
                              hipStream_t stream) {
    const float* x       = (const float*)d_in[0];
    const int*   ei0     = (const int*)d_in[1];
    const int*   ei1     = (const int*)d_in[2];
    const int*   ei2     = (const int*)d_in[3];
    const int*   parent1 = (const int*)d_in[4];
    const int*   parent2 = (const int*)d_in[5];
    const float* W0 = (const float*)d_in[6];
    const float* b0 = (const float*)d_in[7];
    const float* W1 = (const float*)d_in[8];
    const float* b1 = (const float*)d_in[9];
    const float* W2 = (const float*)d_in[10];
    const float* b2 = (const float*)d_in[11];
    const float* W3 = (const float*)d_in[12];
    const float* b3 = (const float*)d_in[13];
    const float* W4 = (const float*)d_in[14];
    const float* b4 = (const float*)d_in[15];
    const float* pW = (const float*)d_in[16];
    const float* pb = (const float*)d_in[17];
    const float* pg = (const float*)d_in[18];
    const float* pbeta = (const float*)d_in[19];
    const float* pmean = (const float*)d_in[20];
    const float* pvar  = (const float*)d_in[21];
    float* out = (float*)d_out;

    char* ws = (char*)d_ws;
    size_t off = 0;
    auto alloc = [&](size_t nbytes) -> char* {
        char* p = ws + off;
        off += ((nbytes + 255) / 256) * 256;
        return p;
    };
    float* dis0 = (float*)alloc(N0 * 4);
    float* dis1 = (float*)alloc(N1 * 4);
    float* dis2 = (float*)alloc(N2 * 4);
    float* bnscale = (float*)alloc(4 * HDIM * 4);
    float* bnshift = (float*)alloc(4 * HDIM * 4);
    float* W1b = (float*)alloc((size_t)N1 * 10 * 4);
    u32* Y   = (u32*)alloc((size_t)N0 * 64 * 4);
    u32* H0  = (u32*)alloc((size_t)N0 * 64 * 4);
    u32* H1  = (u32*)alloc((size_t)N1 * 64 * 4);
    u32* X1  = (u32*)alloc((size_t)N1 * 64 * 4);
    u32* HU1 = (u32*)alloc((size_t)N1 * 64 * 4);
    u32* U1  = (u32*)alloc((size_t)N1 * 64 * 4);
    u32* X2  = (u32*)alloc((size_t)N2 * 64 * 4);
    u32* H2  = (u32*)alloc((size_t)N2 * 64 * 4);
    u32* U2  = (u32*)alloc((size_t)N2 * 64 * 4);
    u32* V2  = (u32*)alloc((size_t)N2 * 64 * 4);
    u32* Y4p = (u32*)alloc((size_t)N0 * 8 * 4);
    int* rpAll = (int*)alloc((size_t)(OFFT + 1) * 4);
    int* srcU  = (int*)alloc((size_t)S4 * 4);
    int* blockHist = (int*)alloc((size_t)BH_N * 4);
    int* OfsAbs    = (int*)alloc((size_t)(BH_N + 1) * 4);
    u32* binPair   = (u32*)alloc((size_t)S4 * 4);
    int* bsum   = (int*)alloc(NBLK2 * 4);
    int* totalb = (int*)alloc(4);

    const int B = 256;
    auto G = [](long long t) { return (unsigned)((t + 255) / 256); };
    auto G64 = [](long long m) { return (unsigned)((m + 63) / 64); };

    // ---- CSR build ----
    binhist_kernel<<<NBA, B, 0, stream>>>(
        ei0 + E0C, ei1 + E1C, ei2 + E2C, parent1, parent2, blockHist);
    scan_k1<<<NBLK2, B, 0, stream>>>(blockHist, bsum, BH_N);
    scan_k2<<<1, B, 0, stream>>>(bsum, totalb, NBLK2);
    scan_k3<<<NBLK2, B, 0, stream>>>(blockHist, bsum, totalb, OfsAbs, BH_N);
    binfill_kernel<<<NBA, B, 0, stream>>>(
        ei0, ei0 + E0C, ei1, ei1 + E1C, ei2, ei2 + E2C, parent1, parent2, OfsAbs, binPair);
    bucket_build_kernel<<<NBUCK, 1024, 0, stream>>>(
        binPair, OfsAbs, rpAll, srcU, dis0, dis1, dis2);
    bn_pre_kernel<<<2, B, 0, stream>>>(pg, pbeta, pmean, pvar, bnscale, bnshift);

    // ---- gcn0 ----
    mm128_kernel<<<G64(N0), B, 0, stream>>>(
        x, W0, Y, N0, dis0, nullptr, nullptr, nullptr, nullptr, nullptr, 0, 1,
        nullptr, nullptr, 0);
    gather128_kernel<<<G((long long)N0 * 64), B, 0, stream>>>(rpAll + OFF0, srcU, Y, dis0, b0, H0, N0);

    // ---- pool1 (fused segment-sum + matmul) ----
    mm128_kernel<<<G64(N1), B, 0, stream>>>(
        H0, pW, X1, N1, nullptr, nullptr, nullptr, pb, bnscale, bnshift, 1, 0,
        rpAll + OFF3, srcU, 1);

    // ---- gcn1 ----
    mm128_kernel<<<G64(N1), B, 0, stream>>>(
        X1, W1, Y, N1, dis1, nullptr, nullptr, nullptr, nullptr, nullptr, 0, 0,
        nullptr, nullptr, 0);
    gather128_kernel<<<G((long long)N1 * 64), B, 0, stream>>>(rpAll + OFF1, srcU, Y, dis1, b1, H1, N1);

    // ---- pool2 (fused) ----
    mm128_kernel<<<G64(N2), B, 0, stream>>>(
        H1, pW + 128 * 128, X2, N2, nullptr, nullptr, nullptr, pb + 128, bnscale + 128, bnshift + 128, 1, 0,
        rpAll + OFF4, srcU, 1);

    // ---- gcn2 ----
    mm128_kernel<<<G64(N2), B, 0, stream>>>(
        X2, W2, Y, N2, dis2, nullptr, nullptr, nullptr, nullptr, nullptr, 0, 0,
        nullptr, nullptr, 0);
    gather128_kernel<<<G((long long)N2 * 64), B, 0, stream>>>(rpAll + OFF2, srcU, Y, dis2, b2, H2, N2);

    // ---- up level 2 ----
    mm128_kernel<<<G64(N2), B, 0, stream>>>(
        H2, pW + 2 * 128 * 128, U2, N2, nullptr, nullptr, nullptr, pb + 256, bnscale + 256, bnshift + 256, 1, 0,
        nullptr, nullptr, 0);
    mm128_kernel<<<G64(N2), B, 0, stream>>>(
        U2, W3, V2, N2, nullptr, nullptr, nullptr, nullptr, nullptr, nullptr, 0, 0,
        nullptr, nullptr, 0);

    // ---- gcn3 ----
    mm128_kernel<<<G64(N1), B, 0, stream>>>(
        H1, W3 + 128 * 128, Y, N1, dis1, V2, parent2, nullptr, nullptr, nullptr, 0, 0,
        nullptr, nullptr, 0);
    gather128_kernel<<<G((long long)N1 * 64), B, 0, stream>>>(rpAll + OFF1, srcU, Y, dis1, b3, HU1, N1);

    // ---- up level 1 ----
    mm128_kernel<<<G64(N1), B, 0, stream>>>(
        HU1, pW + 3 * 128 * 128, U1, N1, nullptr, nullptr, nullptr, pb + 384, bnscale + 384, bnshift + 384, 1, 0,
        nullptr, nullptr, 0);
    mm10_kernel<<<G(N1), B, 0, stream>>>(U1, W4, W1b, N1);

    // ---- gcn4 ----
    mm10p_kernel<<<G(N0), B, 0, stream>>>(H0, W4 + 128 * 10, Y4p, N0, dis0, W1b, parent1);
    gather10_lsm_kernel<<<G(N0), B, 0, stream>>>(rpAll + OFF0, srcU, Y4p, dis0, b4, out, N0);
}